// Round 1
// baseline (676.426 us; speedup 1.0000x reference)
//
#include <hip/hip_runtime.h>
#include <stdint.h>

typedef unsigned short u16;
typedef __attribute__((ext_vector_type(8))) short short8;
typedef __attribute__((ext_vector_type(4))) float f32x4;
typedef __attribute__((ext_vector_type(4))) unsigned short u16x4;

constexpr int CB = 4, CS = 1024, CD = 3584, CN = 28, CK = 4, CH = 128, CG = 7;
constexpr int CT = CB * CS;                    // 4096 tokens
constexpr int QKVC = CN * CH + 2 * CK * CH;    // 4608 fused qkv cols
constexpr long KV_HALF = (long)CB * CS * CK * CH; // 2,097,152 floats per cache half

__device__ __forceinline__ u16 f2bf(float f) {
  union { float f; uint32_t u; } c; c.f = f;
  uint32_t u = c.u + 0x7fffu + ((c.u >> 16) & 1);   // RNE to bf16
  return (u16)(u >> 16);
}

// async global->LDS, 16B per lane; LDS dest must be wave-uniform base (+lane*16 implicit)
__device__ __forceinline__ void gload16(const void* g, void* l) {
  __builtin_amdgcn_global_load_lds(
      (const __attribute__((address_space(1))) unsigned int*)(uintptr_t)g,
      (__attribute__((address_space(3))) unsigned int*)(uint32_t)(uintptr_t)l,
      16, 0, 0);
}

// ---------------- f32 -> bf16 bulk convert ----------------
__global__ __launch_bounds__(256) void cvt_bf16_kernel(const float* __restrict__ in,
                                                       u16* __restrict__ outp, long n) {
  long i = ((long)blockIdx.x * 256 + threadIdx.x) * 4;
  if (i < n) {
    const float4 v = *(const float4*)(in + i);
    u16x4 o; o.x = f2bf(v.x); o.y = f2bf(v.y); o.z = f2bf(v.z); o.w = f2bf(v.w);
    *(u16x4*)(outp + i) = o;
  }
}

// ---------------- tiled transpose f32[R][C] -> bf16 dst[(dstOff+c)][R] ----------------
__global__ __launch_bounds__(256) void transpose_cvt_kernel(const float* __restrict__ src,
                                                            u16* __restrict__ dst,
                                                            int R, int C, int dstOff) {
  __shared__ float tile[32][33];
  const int c0 = blockIdx.x * 32, r0 = blockIdx.y * 32;
  const int tx = threadIdx.x, ty = threadIdx.y;
#pragma unroll
  for (int i = ty; i < 32; i += 8)
    tile[i][tx] = src[(long)(r0 + i) * C + c0 + tx];
  __syncthreads();
#pragma unroll
  for (int i = ty; i < 32; i += 8)
    dst[(long)(dstOff + c0 + i) * R + r0 + tx] = f2bf(tile[tx][i]);
}

// ---------------- m97-structure bf16 GEMM: C[M][Ncol] = A[M][Kd] * Bt[Ncol][Kd]^T (+bias) ----------------
template <int ADD_BIAS>
__global__ __launch_bounds__(256) void gemm_bt_kernel(const u16* __restrict__ A,
                                                      const u16* __restrict__ Bt,
                                                      float* __restrict__ C,
                                                      const float* __restrict__ bq,
                                                      const float* __restrict__ bk2,
                                                      const float* __restrict__ bv,
                                                      int Ncol, int Kd) {
  __shared__ u16 As[128 * 32];
  __shared__ u16 Bs[128 * 32];
  const int tid = threadIdx.x;
  const int wid = tid >> 6, lane = tid & 63;
  const int g = lane >> 4, r = lane & 15;
  const int bm = blockIdx.x * 128, bn = blockIdx.y * 128;
  const int wm = (wid >> 1) * 64, wn = (wid & 1) * 64;

  f32x4 acc[4][4];
#pragma unroll
  for (int mi = 0; mi < 4; ++mi)
#pragma unroll
    for (int ni = 0; ni < 4; ++ni) acc[mi][ni] = f32x4{0.f, 0.f, 0.f, 0.f};

  const int srow = wid * 16 + (lane >> 2);
  const int scol = (lane & 3) * 8;
  const u16* gA = A + (long)(bm + srow) * Kd + scol;
  const u16* gB = Bt + (long)(bn + srow) * Kd + scol;
  u16* lA = As + wid * 512;
  u16* lB = Bs + wid * 512;
  const long rowskip = (long)64 * Kd;

  for (int k0 = 0; k0 < Kd; k0 += 32) {
    __syncthreads();
    gload16(gA + k0, lA);
    gload16(gA + k0 + rowskip, lA + 2048);
    gload16(gB + k0, lB);
    gload16(gB + k0 + rowskip, lB + 2048);
    __syncthreads();
    short8 af[4], bf[4];
#pragma unroll
    for (int mi = 0; mi < 4; ++mi) af[mi] = *(const short8*)&As[(wm + mi * 16 + r) * 32 + g * 8];
#pragma unroll
    for (int ni = 0; ni < 4; ++ni) bf[ni] = *(const short8*)&Bs[(wn + ni * 16 + r) * 32 + g * 8];
#pragma unroll
    for (int mi = 0; mi < 4; ++mi)
#pragma unroll
      for (int ni = 0; ni < 4; ++ni)
        acc[mi][ni] = __builtin_amdgcn_mfma_f32_16x16x32_bf16(af[mi], bf[ni], acc[mi][ni], 0, 0, 0);
  }

#pragma unroll
  for (int mi = 0; mi < 4; ++mi) {
#pragma unroll
    for (int ni = 0; ni < 4; ++ni) {
      const int col = bn + wn + ni * 16 + r;
      float badd = 0.f;
      if (ADD_BIAS)
        badd = (col < CN * CH) ? bq[col]
             : (col < CN * CH + CK * CH) ? bk2[col - CN * CH]
                                         : bv[col - CN * CH - CK * CH];
#pragma unroll
      for (int j = 0; j < 4; ++j) {
        const int row = bm + wm + mi * 16 + g * 4 + j;
        C[(long)row * Ncol + col] = acc[mi][ni][j] + badd;
      }
    }
  }
}

// ---------------- RoPE + scatter: q->bf16 [B][N][S][H], k->cache f32 + bf16 [B][K][S][H] ----------------
__global__ __launch_bounds__(256) void rope_scatter_kernel(const float* __restrict__ qkv,
                                                           const int* __restrict__ positions,
                                                           u16* __restrict__ qb,
                                                           u16* __restrict__ kb,
                                                           float* __restrict__ cacheK) {
  const int t = blockIdx.x;
  const int b = t / CS, s = t % CS;
  __shared__ float csv[64], snv[64];
  if (threadIdx.x < 64) {
    const int h = threadIdx.x;
    const float inv = exp2f(-(float)h * (19.931568569324174f / 64.0f)); // 1e6^(-h/64)
    const float fr = (float)positions[t] * inv;
    csv[h] = cosf(fr);
    snv[h] = sinf(fr);
  }
  __syncthreads();
  const float* row = qkv + (long)t * QKVC;
  for (int p = threadIdx.x; p < CN * 64; p += 256) {
    const int n = p >> 6, h = p & 63;
    const float x1 = row[n * CH + h], x2 = row[n * CH + h + 64];
    const float o1 = x1 * csv[h] - x2 * snv[h];
    const float o2 = x2 * csv[h] + x1 * snv[h];
    const long qi = ((long)(b * CN + n) * CS + s) * CH + h;
    qb[qi] = f2bf(o1);
    qb[qi + 64] = f2bf(o2);
  }
  for (int p = threadIdx.x; p < CK * 64; p += 256) {
    const int kk = p >> 6, h = p & 63;
    const float x1 = row[CN * CH + kk * CH + h], x2 = row[CN * CH + kk * CH + h + 64];
    const float o1 = x1 * csv[h] - x2 * snv[h];
    const float o2 = x2 * csv[h] + x1 * snv[h];
    const long ci = ((long)(b * CS + s) * CK + kk) * CH + h;
    cacheK[ci] = o1;
    cacheK[ci + 64] = o2;
    const long ki = ((long)(b * CK + kk) * CS + s) * CH + h;
    kb[ki] = f2bf(o1);
    kb[ki + 64] = f2bf(o2);
  }
}

// ---------------- V: cache f32 write + transposed bf16 [B][K][H][S] ----------------
__global__ __launch_bounds__(256) void v_transpose_kernel(const float* __restrict__ qkv,
                                                          float* __restrict__ cacheV,
                                                          u16* __restrict__ vt) {
  __shared__ float tile[32][33];
  const int s0 = blockIdx.x * 32, h0 = blockIdx.y * 32;
  const int bz = blockIdx.z;                 // b*K + kk
  const int b = bz >> 2, kk = bz & 3;
  const int tx = threadIdx.x, ty = threadIdx.y;
#pragma unroll
  for (int i = ty; i < 32; i += 8) {
    const int s = s0 + i;
    const float v = qkv[(long)(b * CS + s) * QKVC + CN * CH + CK * CH + kk * CH + h0 + tx];
    cacheV[((long)(b * CS + s) * CK + kk) * CH + h0 + tx] = v;
    tile[i][tx] = v;
  }
  __syncthreads();
#pragma unroll
  for (int i = ty; i < 32; i += 8)
    vt[((long)bz * CH + h0 + i) * CS + s0 + tx] = f2bf(tile[tx][i]);
}

// ---------------- flash attention: swapped-QK^T, online softmax, PV ----------------
__global__ __launch_bounds__(256) void attn_kernel(const u16* __restrict__ qg,
                                                   const u16* __restrict__ kg,
                                                   const u16* __restrict__ vtg,
                                                   u16* __restrict__ og) {
  __shared__ u16 Ks[32][128];   // K tile  [kv][h]
  __shared__ u16 Vt[128][32];   // V^T tile [h][kv]
  __shared__ u16 Pl[4][16][32]; // per-wave P slab [q][kv]

  const int bn = blockIdx.y;                 // b*N + n
  const int b = bn / CN, n = bn % CN;
  const int kvh = n / CG;
  const int q0 = blockIdx.x * 64;
  const int tid = threadIdx.x;
  const int wid = tid >> 6, lane = tid & 63;
  const int g = lane >> 4, r = lane & 15;
  const int wq0 = q0 + wid * 16;
  const int qrow = wq0 + r;

  short8 qf[4];
  const u16* qrp = qg + ((long)bn * CS + qrow) * CH;
#pragma unroll
  for (int c = 0; c < 4; ++c) qf[c] = *(const short8*)(qrp + c * 32 + g * 8);

  const u16* kbase = kg + (long)(b * CK + kvh) * CS * CH;   // [S][H]
  const u16* vbase = vtg + (long)(b * CK + kvh) * CH * CS;  // [H][S]

  f32x4 oacc[8];
#pragma unroll
  for (int c = 0; c < 8; ++c) oacc[c] = f32x4{0.f, 0.f, 0.f, 0.f};
  float mrun = -INFINITY, lsum = 0.f;

  const float c1 = 0.08838834764831845f * 1.4426950408889634f; // (1/sqrt(128))*log2(e)

  const int nsteps = (q0 + 64) / 32;
  for (int it = 0; it < nsteps; ++it) {
    const int j0 = it * 32;
    __syncthreads();
    { // stage K tile: contiguous 8KB
      const u16* src = kbase + (long)j0 * CH;
      u16* lk = &Ks[0][0] + wid * 512;
      gload16(src + wid * 512 + lane * 8, lk);
      gload16(src + 2048 + wid * 512 + lane * 8, lk + 2048);
    }
    { // stage V^T tile: [128][32], rows of 64B
      u16* lv = &Vt[0][0] + wid * 512;
      const int hh = wid * 16 + (lane >> 2);
      const int sc = (lane & 3) * 8;
      gload16(vbase + (long)hh * CS + j0 + sc, lv);
      gload16(vbase + (long)(hh + 64) * CS + j0 + sc, lv + 2048);
    }
    __syncthreads();
    if (j0 > wq0 + 15) continue;  // wave fully above diagonal; still hits next loop barrier

    // S = K·Q^T  (lane holds scores for q-row r, kv = j0+16*m2+4g+j)
    float tvals[8];
#pragma unroll
    for (int m2 = 0; m2 < 2; ++m2) {
      f32x4 acc = f32x4{0.f, 0.f, 0.f, 0.f};
#pragma unroll
      for (int c = 0; c < 4; ++c) {
        short8 kf = *(const short8*)&Ks[m2 * 16 + r][c * 32 + g * 8];
        acc = __builtin_amdgcn_mfma_f32_16x16x32_bf16(kf, qf[c], acc, 0, 0, 0);
      }
#pragma unroll
      for (int j = 0; j < 4; ++j) {
        const int kv = j0 + m2 * 16 + g * 4 + j;
        const float v = acc[j] * c1;
        tvals[m2 * 4 + j] = (kv <= qrow) ? v : -INFINITY;
      }
    }

    float rmax = tvals[0];
#pragma unroll
    for (int i = 1; i < 8; ++i) rmax = fmaxf(rmax, tvals[i]);
    rmax = fmaxf(rmax, __shfl_xor(rmax, 16));
    rmax = fmaxf(rmax, __shfl_xor(rmax, 32));
    const float mnew = fmaxf(mrun, rmax);
    const float fac = exp2f(mrun - mnew);
    float ps[8], rsum = 0.f;
#pragma unroll
    for (int i = 0; i < 8; ++i) { ps[i] = exp2f(tvals[i] - mnew); rsum += ps[i]; }
    rsum += __shfl_xor(rsum, 16);
    rsum += __shfl_xor(rsum, 32);
    lsum = lsum * fac + rsum;
    mrun = mnew;

    // P -> per-wave LDS slab (C-layout) then read back as PV A-fragment
#pragma unroll
    for (int m2 = 0; m2 < 2; ++m2) {
      uint2 pk;
      pk.x = (uint32_t)f2bf(ps[m2 * 4 + 0]) | ((uint32_t)f2bf(ps[m2 * 4 + 1]) << 16);
      pk.y = (uint32_t)f2bf(ps[m2 * 4 + 2]) | ((uint32_t)f2bf(ps[m2 * 4 + 3]) << 16);
      *(uint2*)&Pl[wid][r][m2 * 16 + g * 4] = pk;
    }
    const short8 pf = *(const short8*)&Pl[wid][r][g * 8];

    // rescale o by per-q factor (o rows live at q=4g+j; factor lives at lane q)
#pragma unroll
    for (int j = 0; j < 4; ++j) {
      const float fj = __shfl(fac, g * 4 + j);
#pragma unroll
      for (int c = 0; c < 8; ++c) oacc[c][j] *= fj;
    }

    // O += P·V
#pragma unroll
    for (int c = 0; c < 8; ++c) {
      const short8 vf = *(const short8*)&Vt[c * 16 + r][g * 8];
      oacc[c] = __builtin_amdgcn_mfma_f32_16x16x32_bf16(pf, vf, oacc[c], 0, 0, 0);
    }
  }

  // normalize + write attn output bf16 [t][n*H+h]
  float linv[4];
#pragma unroll
  for (int j = 0; j < 4; ++j) {
    const float lq = __shfl(lsum, g * 4 + j);
    linv[j] = 1.0f / lq;
  }
#pragma unroll
  for (int c = 0; c < 8; ++c)
#pragma unroll
    for (int j = 0; j < 4; ++j) {
      const long t = (long)b * CS + wq0 + g * 4 + j;
      og[t * (CN * CH) + n * CH + c * 16 + r] = f2bf(oacc[c][j] * linv[j]);
    }
}

// ---------------- host ----------------
extern "C" void kernel_launch(void* const* d_in, const int* in_sizes, int n_in,
                              void* d_out, int out_size, void* d_ws, size_t ws_size,
                              hipStream_t stream) {
  (void)in_sizes; (void)n_in; (void)out_size; (void)ws_size;
  const float* x  = (const float*)d_in[1];
  const int* positions = (const int*)d_in[2];
  const float* Wq = (const float*)d_in[3];
  const float* bq = (const float*)d_in[4];
  const float* Wk = (const float*)d_in[5];
  const float* bk = (const float*)d_in[6];
  const float* Wv = (const float*)d_in[7];
  const float* bv = (const float*)d_in[8];
  const float* Wo = (const float*)d_in[9];
  float* out = (float*)d_out;

  char* ws = (char*)d_ws;
  u16*   xb     = (u16*)(ws + 0L);            // 29,360,128 B  x bf16 [T][D]
  u16*   w1t    = (u16*)(ws + 29360128L);     // 33,030,144 B  W_qkv^T bf16 [4608][3584]
  u16*   wot    = (u16*)(ws + 62390272L);     // 25,690,112 B  Wo^T bf16 [3584][3584]
  float* qkv    = (float*)(ws + 88080384L);   // 75,497,472 B  qkv f32 [T][4608]
  u16*   attn_b = (u16*)qkv;                  // aliased: attn out bf16 [T][3584] (qkv dead by then)
  u16*   qb     = (u16*)(ws + 163577856L);    // 29,360,128 B  q roped bf16 [B][N][S][H]
  u16*   kb2    = (u16*)(ws + 192937984L);    //  4,194,304 B  k roped bf16 [B][K][S][H]
  u16*   vt     = (u16*)(ws + 197132288L);    //  4,194,304 B  V^T bf16 [B][K][H][S]
  // total 201,326,592 B

  cvt_bf16_kernel<<<dim3((CT * (long)CD) / 1024), 256, 0, stream>>>(x, xb, (long)CT * CD);
  transpose_cvt_kernel<<<dim3(112, 112), dim3(32, 8), 0, stream>>>(Wq, w1t, CD, CN * CH, 0);
  transpose_cvt_kernel<<<dim3(16, 112), dim3(32, 8), 0, stream>>>(Wk, w1t, CD, CK * CH, CN * CH);
  transpose_cvt_kernel<<<dim3(16, 112), dim3(32, 8), 0, stream>>>(Wv, w1t, CD, CK * CH, CN * CH + CK * CH);
  transpose_cvt_kernel<<<dim3(112, 112), dim3(32, 8), 0, stream>>>(Wo, wot, CN * CH, CD, 0);

  gemm_bt_kernel<1><<<dim3(CT / 128, QKVC / 128), 256, 0, stream>>>(xb, w1t, qkv, bq, bk, bv, QKVC, CD);

  rope_scatter_kernel<<<dim3(CT), 256, 0, stream>>>(qkv, positions, qb, kb2, out);
  v_transpose_kernel<<<dim3(CS / 32, CH / 32, CB * CK), dim3(32, 8), 0, stream>>>(qkv, out + KV_HALF, vt);

  attn_kernel<<<dim3(CS / 64, CB * CN), 256, 0, stream>>>(qb, kb2, vt, attn_b);

  gemm_bt_kernel<0><<<dim3(CT / 128, CD / 128), 256, 0, stream>>>(attn_b, wot, out + 2 * KV_HALF,
                                                                  nullptr, nullptr, nullptr, CD, CD);
}

// Round 3
// 641.519 us; speedup vs baseline: 1.0544x; 1.0544x over previous
//
#include <hip/hip_runtime.h>
#include <stdint.h>

typedef unsigned short u16;
typedef __attribute__((ext_vector_type(8))) short short8;
typedef __attribute__((ext_vector_type(4))) float f32x4;
typedef __attribute__((ext_vector_type(4))) unsigned short u16x4;

constexpr int CB = 4, CS = 1024, CD = 3584, CN = 28, CK = 4, CH = 128, CG = 7;
constexpr int CT = CB * CS;                    // 4096 tokens
constexpr int QKVC = CN * CH + 2 * CK * CH;    // 4608 fused qkv cols
constexpr long KV_HALF = (long)CB * CS * CK * CH; // 2,097,152 floats per cache half

__device__ __forceinline__ u16 f2bf(float f) {
  union { float f; uint32_t u; } c; c.f = f;
  uint32_t u = c.u + 0x7fffu + ((c.u >> 16) & 1);   // RNE to bf16
  return (u16)(u >> 16);
}

// async global->LDS, 16B per lane; LDS dest must be wave-uniform base (+lane*16 implicit)
__device__ __forceinline__ void gload16(const void* g, void* l) {
  __builtin_amdgcn_global_load_lds(
      (const __attribute__((address_space(1))) unsigned int*)(uintptr_t)g,
      (__attribute__((address_space(3))) unsigned int*)(uint32_t)(uintptr_t)l,
      16, 0, 0);
}

// ---------------- f32 -> bf16 bulk convert ----------------
__global__ __launch_bounds__(256) void cvt_bf16_kernel(const float* __restrict__ in,
                                                       u16* __restrict__ outp, long n) {
  long i = ((long)blockIdx.x * 256 + threadIdx.x) * 4;
  if (i < n) {
    const float4 v = *(const float4*)(in + i);
    u16x4 o; o.x = f2bf(v.x); o.y = f2bf(v.y); o.z = f2bf(v.z); o.w = f2bf(v.w);
    *(u16x4*)(outp + i) = o;
  }
}

// ---------------- tiled transpose f32[R][C] -> bf16 dst[(dstOff+c)][R] ----------------
__global__ __launch_bounds__(256) void transpose_cvt_kernel(const float* __restrict__ src,
                                                            u16* __restrict__ dst,
                                                            int R, int C, int dstOff) {
  __shared__ float tile[32][33];
  const int c0 = blockIdx.x * 32, r0 = blockIdx.y * 32;
  const int tx = threadIdx.x, ty = threadIdx.y;
#pragma unroll
  for (int i = ty; i < 32; i += 8)
    tile[i][tx] = src[(long)(r0 + i) * C + c0 + tx];
  __syncthreads();
#pragma unroll
  for (int i = ty; i < 32; i += 8)
    dst[(long)(dstOff + c0 + i) * R + r0 + tx] = f2bf(tile[tx][i]);
}

// ---------------- m97-structure bf16 GEMM: C[M][Ncol] = A[M][Kd] * Bt[Ncol][Kd]^T (+bias) ----------------
template <int ADD_BIAS>
__global__ __launch_bounds__(256) void gemm_bt_kernel(const u16* __restrict__ A,
                                                      const u16* __restrict__ Bt,
                                                      float* __restrict__ C,
                                                      const float* __restrict__ bq,
                                                      const float* __restrict__ bk2,
                                                      const float* __restrict__ bv,
                                                      int Ncol, int Kd) {
  __shared__ u16 As[128 * 32];
  __shared__ u16 Bs[128 * 32];
  const int tid = threadIdx.x;
  const int wid = tid >> 6, lane = tid & 63;
  const int g = lane >> 4, r = lane & 15;
  const int bm = blockIdx.x * 128, bn = blockIdx.y * 128;
  const int wm = (wid >> 1) * 64, wn = (wid & 1) * 64;

  f32x4 acc[4][4];
#pragma unroll
  for (int mi = 0; mi < 4; ++mi)
#pragma unroll
    for (int ni = 0; ni < 4; ++ni) acc[mi][ni] = f32x4{0.f, 0.f, 0.f, 0.f};

  const int srow = wid * 16 + (lane >> 2);
  const int scol = (lane & 3) * 8;
  const u16* gA = A + (long)(bm + srow) * Kd + scol;
  const u16* gB = Bt + (long)(bn + srow) * Kd + scol;
  u16* lA = As + wid * 512;
  u16* lB = Bs + wid * 512;
  const long rowskip = (long)64 * Kd;

  for (int k0 = 0; k0 < Kd; k0 += 32) {
    __syncthreads();
    gload16(gA + k0, lA);
    gload16(gA + k0 + rowskip, lA + 2048);
    gload16(gB + k0, lB);
    gload16(gB + k0 + rowskip, lB + 2048);
    __syncthreads();
    short8 af[4], bf[4];
#pragma unroll
    for (int mi = 0; mi < 4; ++mi) af[mi] = *(const short8*)&As[(wm + mi * 16 + r) * 32 + g * 8];
#pragma unroll
    for (int ni = 0; ni < 4; ++ni) bf[ni] = *(const short8*)&Bs[(wn + ni * 16 + r) * 32 + g * 8];
#pragma unroll
    for (int mi = 0; mi < 4; ++mi)
#pragma unroll
      for (int ni = 0; ni < 4; ++ni)
        acc[mi][ni] = __builtin_amdgcn_mfma_f32_16x16x32_bf16(af[mi], bf[ni], acc[mi][ni], 0, 0, 0);
  }

#pragma unroll
  for (int mi = 0; mi < 4; ++mi) {
#pragma unroll
    for (int ni = 0; ni < 4; ++ni) {
      const int col = bn + wn + ni * 16 + r;
      float badd = 0.f;
      if (ADD_BIAS)
        badd = (col < CN * CH) ? bq[col]
             : (col < CN * CH + CK * CH) ? bk2[col - CN * CH]
                                         : bv[col - CN * CH - CK * CH];
#pragma unroll
      for (int j = 0; j < 4; ++j) {
        const int row = bm + wm + mi * 16 + g * 4 + j;
        C[(long)row * Ncol + col] = acc[mi][ni][j] + badd;
      }
    }
  }
}

// ---------------- RoPE + scatter: q->bf16 (pre-scaled) [B][N][S][H], k->cache f32 + bf16 [B][K][S][H] ----------------
__global__ __launch_bounds__(256) void rope_scatter_kernel(const float* __restrict__ qkv,
                                                           const int* __restrict__ positions,
                                                           u16* __restrict__ qb,
                                                           u16* __restrict__ kb,
                                                           float* __restrict__ cacheK) {
  const int t = blockIdx.x;
  const int b = t / CS, s = t % CS;
  __shared__ float csv[64], snv[64];
  if (threadIdx.x < 64) {
    const int h = threadIdx.x;
    const float inv = exp2f(-(float)h * (19.931568569324174f / 64.0f)); // 1e6^(-h/64)
    const float fr = (float)positions[t] * inv;
    csv[h] = cosf(fr);
    snv[h] = sinf(fr);
  }
  __syncthreads();
  // fold softmax scale * log2(e) into q so attention scores are exp2-ready
  const float SCQ = 0.08838834764831845f * 1.4426950408889634f;
  const float* row = qkv + (long)t * QKVC;
  for (int p = threadIdx.x; p < CN * 64; p += 256) {
    const int n = p >> 6, h = p & 63;
    const float x1 = row[n * CH + h], x2 = row[n * CH + h + 64];
    const float o1 = (x1 * csv[h] - x2 * snv[h]) * SCQ;
    const float o2 = (x2 * csv[h] + x1 * snv[h]) * SCQ;
    const long qi = ((long)(b * CN + n) * CS + s) * CH + h;
    qb[qi] = f2bf(o1);
    qb[qi + 64] = f2bf(o2);
  }
  for (int p = threadIdx.x; p < CK * 64; p += 256) {
    const int kk = p >> 6, h = p & 63;
    const float x1 = row[CN * CH + kk * CH + h], x2 = row[CN * CH + kk * CH + h + 64];
    const float o1 = x1 * csv[h] - x2 * snv[h];
    const float o2 = x2 * csv[h] + x1 * snv[h];
    const long ci = ((long)(b * CS + s) * CK + kk) * CH + h;
    cacheK[ci] = o1;
    cacheK[ci + 64] = o2;
    const long ki = ((long)(b * CK + kk) * CS + s) * CH + h;
    kb[ki] = f2bf(o1);
    kb[ki + 64] = f2bf(o2);
  }
}

// ---------------- V: cache f32 write + transposed bf16 [B][K][H][S] ----------------
__global__ __launch_bounds__(256) void v_transpose_kernel(const float* __restrict__ qkv,
                                                          float* __restrict__ cacheV,
                                                          u16* __restrict__ vt) {
  __shared__ float tile[32][33];
  const int s0 = blockIdx.x * 32, h0 = blockIdx.y * 32;
  const int bz = blockIdx.z;                 // b*K + kk
  const int b = bz >> 2, kk = bz & 3;
  const int tx = threadIdx.x, ty = threadIdx.y;
#pragma unroll
  for (int i = ty; i < 32; i += 8) {
    const int s = s0 + i;
    const float v = qkv[(long)(b * CS + s) * QKVC + CN * CH + CK * CH + kk * CH + h0 + tx];
    cacheV[((long)(b * CS + s) * CK + kk) * CH + h0 + tx] = v;
    tile[i][tx] = v;
  }
  __syncthreads();
#pragma unroll
  for (int i = ty; i < 32; i += 8)
    vt[((long)bz * CH + h0 + i) * CS + s0 + tx] = f2bf(tile[tx][i]);
}

// ---------------- flash attention: 4 waves x 32 q-rows, 64 kv/step, XOR-swizzled LDS ----------------
// P slab row stride: 64 kv + 8 pad = 72 u16 (144B = 9*16B, keeps short8 reads 16B-aligned)
constexpr int PSTR = 72;
__global__ __launch_bounds__(256) void attn_kernel(const u16* __restrict__ qg,
                                                   const u16* __restrict__ kg,
                                                   const u16* __restrict__ vtg,
                                                   u16* __restrict__ og) {
  __shared__ u16 Ks[64 * 128];        // K tile [kv][h], 16B chunks XOR-swizzled by (row&7)
  __shared__ u16 Vt[128 * 64];        // V^T tile [h][kv], 16B chunks XOR-swizzled by (row&7)
  __shared__ u16 Pl[4 * 32 * PSTR];   // per-wave P slab [q][kv0..63]

  const int bn = blockIdx.y;                 // b*N + n
  const int b = bn / CN, n = bn % CN;
  const int kvh = n / CG;
  const int q0 = ((int)gridDim.x - 1 - (int)blockIdx.x) * 128;  // long blocks first
  const int tid = threadIdx.x;
  const int wid = tid >> 6, lane = tid & 63;
  const int g = lane >> 4, r = lane & 15;
  const int wq0 = q0 + wid * 32;

  // Q fragments for 32 rows (2 x 16-row tiles), kept in registers
  short8 qf[2][4];
#pragma unroll
  for (int qt = 0; qt < 2; ++qt) {
    const u16* qrp = qg + ((long)bn * CS + wq0 + qt * 16 + r) * CH;
#pragma unroll
    for (int c = 0; c < 4; ++c) qf[qt][c] = *(const short8*)(qrp + c * 32 + g * 8);
  }

  const u16* kbase = kg + (long)(b * CK + kvh) * CS * CH;   // [S][H]
  const u16* vbase = vtg + (long)(b * CK + kvh) * CH * CS;  // [H][S]

  f32x4 oacc[2][8];
#pragma unroll
  for (int qt = 0; qt < 2; ++qt)
#pragma unroll
    for (int c = 0; c < 8; ++c) oacc[qt][c] = f32x4{0.f, 0.f, 0.f, 0.f};
  float m[2] = {-INFINITY, -INFINITY};
  float l[2] = {0.f, 0.f};

  const int nsteps = q0 / 64 + 2;
  for (int it = 0; it < nsteps; ++it) {
    const int j0 = it * 64;
    __syncthreads();
    // ---- stage K tile (16KB): linear LDS dest, inverse-swizzled global src ----
#pragma unroll
    for (int c = 0; c < 4; ++c) {
      const int pbase = (wid * 4 + c) * 1024;
      const int p = pbase + lane * 16;
      const int row = p >> 8;                      // 256B per row
      const int chl = ((p >> 4) & 15) ^ (row & 7); // logical 16B-chunk
      gload16(kbase + (long)(j0 + row) * CH + (chl << 3), &Ks[pbase >> 1]);
    }
    // ---- stage V^T tile (16KB) ----
#pragma unroll
    for (int c = 0; c < 4; ++c) {
      const int pbase = (wid * 4 + c) * 1024;
      const int p = pbase + lane * 16;
      const int row = p >> 7;                      // 128B per row
      const int chl = ((p >> 4) & 7) ^ (row & 7);
      gload16(vbase + (long)row * CS + j0 + (chl << 3), &Vt[pbase >> 1]);
    }
    __syncthreads();
    if (j0 > wq0 + 31) continue;   // wave fully above diagonal (barriers already matched)

    // ---- S = K·Q^T : 32 MFMA ----
    f32x4 sc[2][4];
#pragma unroll
    for (int qt = 0; qt < 2; ++qt)
#pragma unroll
      for (int kt = 0; kt < 4; ++kt) sc[qt][kt] = f32x4{0.f, 0.f, 0.f, 0.f};
    __builtin_amdgcn_s_setprio(1);
#pragma unroll
    for (int kt = 0; kt < 4; ++kt) {
      short8 kf[4];
#pragma unroll
      for (int c = 0; c < 4; ++c)
        kf[c] = *(const short8*)&Ks[(kt * 16 + r) * 128 + ((((c << 2) + g) ^ (r & 7)) << 3)];
#pragma unroll
      for (int qt = 0; qt < 2; ++qt)
#pragma unroll
        for (int c = 0; c < 4; ++c)
          sc[qt][kt] = __builtin_amdgcn_mfma_f32_16x16x32_bf16(kf[c], qf[qt][c], sc[qt][kt], 0, 0, 0);
    }
    __builtin_amdgcn_s_setprio(0);

    // ---- causal mask (in place) + row max ----
    float pmax[2];
#pragma unroll
    for (int qt = 0; qt < 2; ++qt) {
      const int qq = wq0 + qt * 16 + r;
#pragma unroll
      for (int kt = 0; kt < 4; ++kt)
#pragma unroll
        for (int j = 0; j < 4; ++j) {
          const int kv = j0 + kt * 16 + g * 4 + j;
          if (kv > qq) sc[qt][kt][j] = -INFINITY;
        }
      float mx = sc[qt][0][0];
#pragma unroll
      for (int kt = 0; kt < 4; ++kt)
#pragma unroll
        for (int j = 0; j < 4; ++j) mx = fmaxf(mx, sc[qt][kt][j]);
      mx = fmaxf(mx, __shfl_xor(mx, 16));
      mx = fmaxf(mx, __shfl_xor(mx, 32));
      pmax[qt] = mx;
    }

    // ---- defer-max: rescale only when max grew beyond threshold ----
    const bool ok = (pmax[0] <= m[0] + 8.f) && (pmax[1] <= m[1] + 8.f);
    if (!__all(ok)) {
#pragma unroll
      for (int qt = 0; qt < 2; ++qt) {
        const float mn = fmaxf(m[qt], pmax[qt]);
        const float fac = exp2f(m[qt] - mn);
        m[qt] = mn;
        l[qt] *= fac;
#pragma unroll
        for (int j = 0; j < 4; ++j) {
          const float fj = __shfl(fac, g * 4 + j);
#pragma unroll
          for (int c = 0; c < 8; ++c) oacc[qt][c][j] *= fj;
        }
      }
    }

    // ---- P = exp2(S - m), row sum, pack to bf16, store to P slab ----
#pragma unroll
    for (int qt = 0; qt < 2; ++qt) {
      float rsum = 0.f;
#pragma unroll
      for (int kt = 0; kt < 4; ++kt) {
        const float p0 = exp2f(sc[qt][kt][0] - m[qt]);
        const float p1 = exp2f(sc[qt][kt][1] - m[qt]);
        const float p2 = exp2f(sc[qt][kt][2] - m[qt]);
        const float p3 = exp2f(sc[qt][kt][3] - m[qt]);
        rsum += (p0 + p1) + (p2 + p3);
        uint2 pk;
        pk.x = (uint32_t)f2bf(p0) | ((uint32_t)f2bf(p1) << 16);
        pk.y = (uint32_t)f2bf(p2) | ((uint32_t)f2bf(p3) << 16);
        *(uint2*)&Pl[wid * 32 * PSTR + (qt * 16 + r) * PSTR + kt * 16 + g * 4] = pk;
      }
      rsum += __shfl_xor(rsum, 16);
      rsum += __shfl_xor(rsum, 32);
      l[qt] += rsum;
    }

    // ---- O += P·V : 32 MFMA ----
    __builtin_amdgcn_s_setprio(1);
#pragma unroll
    for (int ks = 0; ks < 2; ++ks) {
      short8 pfq[2];
#pragma unroll
      for (int qt = 0; qt < 2; ++qt)
        pfq[qt] = *(const short8*)&Pl[wid * 32 * PSTR + (qt * 16 + r) * PSTR + ks * 32 + g * 8];
#pragma unroll
      for (int c = 0; c < 8; ++c) {
        const short8 vf = *(const short8*)&Vt[(c * 16 + r) * 64 + ((((ks << 2) + g) ^ (r & 7)) << 3)];
#pragma unroll
        for (int qt = 0; qt < 2; ++qt)
          oacc[qt][c] = __builtin_amdgcn_mfma_f32_16x16x32_bf16(pfq[qt], vf, oacc[qt][c], 0, 0, 0);
      }
    }
    __builtin_amdgcn_s_setprio(0);
  }

  // ---- normalize + write bf16 [t][n*H+h] ----
#pragma unroll
  for (int qt = 0; qt < 2; ++qt)
#pragma unroll
    for (int j = 0; j < 4; ++j) {
      const float linv = 1.0f / __shfl(l[qt], g * 4 + j);
      const long t = (long)b * CS + wq0 + qt * 16 + g * 4 + j;
#pragma unroll
      for (int c = 0; c < 8; ++c)
        og[t * (CN * CH) + n * CH + c * 16 + r] = f2bf(oacc[qt][c][j] * linv);
    }
}

// ---------------- host ----------------
extern "C" void kernel_launch(void* const* d_in, const int* in_sizes, int n_in,
                              void* d_out, int out_size, void* d_ws, size_t ws_size,
                              hipStream_t stream) {
  (void)in_sizes; (void)n_in; (void)out_size; (void)ws_size;
  const float* x  = (const float*)d_in[1];
  const int* positions = (const int*)d_in[2];
  const float* Wq = (const float*)d_in[3];
  const float* bq = (const float*)d_in[4];
  const float* Wk = (const float*)d_in[5];
  const float* bk = (const float*)d_in[6];
  const float* Wv = (const float*)d_in[7];
  const float* bv = (const float*)d_in[8];
  const float* Wo = (const float*)d_in[9];
  float* out = (float*)d_out;

  char* ws = (char*)d_ws;
  u16*   xb     = (u16*)(ws + 0L);            // 29,360,128 B  x bf16 [T][D]
  u16*   w1t    = (u16*)(ws + 29360128L);     // 33,030,144 B  W_qkv^T bf16 [4608][3584]
  u16*   wot    = (u16*)(ws + 62390272L);     // 25,690,112 B  Wo^T bf16 [3584][3584]
  float* qkv    = (float*)(ws + 88080384L);   // 75,497,472 B  qkv f32 [T][4608]
  u16*   attn_b = (u16*)qkv;                  // aliased: attn out bf16 [T][3584] (qkv dead by then)
  u16*   qb     = (u16*)(ws + 163577856L);    // 29,360,128 B  q roped bf16 [B][N][S][H]
  u16*   kb2    = (u16*)(ws + 192937984L);    //  4,194,304 B  k roped bf16 [B][K][S][H]
  u16*   vt     = (u16*)(ws + 197132288L);    //  4,194,304 B  V^T bf16 [B][K][H][S]
  // total 201,326,592 B

  cvt_bf16_kernel<<<dim3((CT * (long)CD) / 1024), 256, 0, stream>>>(x, xb, (long)CT * CD);
  transpose_cvt_kernel<<<dim3(112, 112), dim3(32, 8), 0, stream>>>(Wq, w1t, CD, CN * CH, 0);
  transpose_cvt_kernel<<<dim3(16, 112), dim3(32, 8), 0, stream>>>(Wk, w1t, CD, CK * CH, CN * CH);
  transpose_cvt_kernel<<<dim3(16, 112), dim3(32, 8), 0, stream>>>(Wv, w1t, CD, CK * CH, CN * CH + CK * CH);
  transpose_cvt_kernel<<<dim3(112, 112), dim3(32, 8), 0, stream>>>(Wo, wot, CN * CH, CD, 0);

  gemm_bt_kernel<1><<<dim3(CT / 128, QKVC / 128), 256, 0, stream>>>(xb, w1t, qkv, bq, bk, bv, QKVC, CD);

  rope_scatter_kernel<<<dim3(CT), 256, 0, stream>>>(qkv, positions, qb, kb2, out);
  v_transpose_kernel<<<dim3(CS / 32, CH / 32, CB * CK), dim3(32, 8), 0, stream>>>(qkv, out + KV_HALF, vt);

  attn_kernel<<<dim3(CS / 128, CB * CN), 256, 0, stream>>>(qb, kb2, vt, attn_b);

  gemm_bt_kernel<0><<<dim3(CT / 128, CD / 128), 256, 0, stream>>>(attn_b, wot, out + 2 * KV_HALF,
                                                                  nullptr, nullptr, nullptr, CD, CD);
}

// Round 4
// 557.108 us; speedup vs baseline: 1.2142x; 1.1515x over previous
//
#include <hip/hip_runtime.h>
#include <stdint.h>

typedef unsigned short u16;
typedef __attribute__((ext_vector_type(8))) short short8;
typedef __attribute__((ext_vector_type(4))) float f32x4;
typedef __attribute__((ext_vector_type(4))) unsigned short u16x4;

constexpr int CB = 4, CS = 1024, CD = 3584, CN = 28, CK = 4, CH = 128, CG = 7;
constexpr int CT = CB * CS;                    // 4096 tokens
constexpr int QKVC = CN * CH + 2 * CK * CH;    // 4608 fused qkv cols
constexpr long KV_HALF = (long)CB * CS * CK * CH; // 2,097,152 floats per cache half

__device__ __forceinline__ u16 f2bf(float f) {
  union { float f; uint32_t u; } c; c.f = f;
  uint32_t u = c.u + 0x7fffu + ((c.u >> 16) & 1);   // RNE to bf16
  return (u16)(u >> 16);
}

// async global->LDS, 16B per lane; LDS dest must be wave-uniform base (+lane*16 implicit)
__device__ __forceinline__ void gload16(const void* g, void* l) {
  __builtin_amdgcn_global_load_lds(
      (const __attribute__((address_space(1))) unsigned int*)(uintptr_t)g,
      (__attribute__((address_space(3))) unsigned int*)(uint32_t)(uintptr_t)l,
      16, 0, 0);
}

// ---------------- f32 -> bf16 bulk convert ----------------
__global__ __launch_bounds__(256) void cvt_bf16_kernel(const float* __restrict__ in,
                                                       u16* __restrict__ outp, long n) {
  long i = ((long)blockIdx.x * 256 + threadIdx.x) * 4;
  if (i < n) {
    const float4 v = *(const float4*)(in + i);
    u16x4 o; o.x = f2bf(v.x); o.y = f2bf(v.y); o.z = f2bf(v.z); o.w = f2bf(v.w);
    *(u16x4*)(outp + i) = o;
  }
}

// ---------------- tiled transpose f32[R][C] -> bf16 dst[(dstOff+c)][R] ----------------
__global__ __launch_bounds__(256) void transpose_cvt_kernel(const float* __restrict__ src,
                                                            u16* __restrict__ dst,
                                                            int R, int C, int dstOff) {
  __shared__ float tile[32][33];
  const int c0 = blockIdx.x * 32, r0 = blockIdx.y * 32;
  const int tx = threadIdx.x, ty = threadIdx.y;
#pragma unroll
  for (int i = ty; i < 32; i += 8)
    tile[i][tx] = src[(long)(r0 + i) * C + c0 + tx];
  __syncthreads();
#pragma unroll
  for (int i = ty; i < 32; i += 8)
    dst[(long)(dstOff + c0 + i) * R + r0 + tx] = f2bf(tile[tx][i]);
}

// ---------------- 256x256 8-phase pipelined bf16 GEMM (T3+T4+T5, counted vmcnt) ----------------
// C[M][Ncol] = A[M][Kd] * Bt[Ncol][Kd]^T (+bias). 512 threads = 8 waves (2M x 4N).
// LDS: per K-tile (BK=64) split into 4 staging units of 16KiB: A-k0, B-k0, A-k1, B-k1,
// each a [256 rows][32 k] slab (64B rows -> bank-balanced ds_read_b128, contiguous gload_lds).
// Pipeline: during tile t's 4 phases stage tile t+1's units in order A0,B0,A1,B1 into buf p^1.
// Entry wait vmcnt(4) -> A0,B0(t) landed; mid wait vmcnt(4) -> A1,B1(t) landed (vmcnt(0) on last).
__device__ __forceinline__ void stage_unit(u16* dst, const u16* src, int rowoff, int Kd,
                                           int kk, int w, int lane) {
  const int ci0 = (w << 7) + lane;        // 16B-chunk index 0..1023; 4 chunks per 64B row
  const int ci1 = ci0 + 64;
  gload16(src + (long)(rowoff + (ci0 >> 2)) * Kd + kk + ((ci0 & 3) << 3), dst + (w << 10));
  gload16(src + (long)(rowoff + (ci1 >> 2)) * Kd + kk + ((ci1 & 3) << 3), dst + (w << 10) + 512);
}

template <int ADD_BIAS>
__global__ __launch_bounds__(512) void gemm256_kernel(const u16* __restrict__ A,
                                                      const u16* __restrict__ Bt,
                                                      float* __restrict__ C,
                                                      const float* __restrict__ bq,
                                                      const float* __restrict__ bk2,
                                                      const float* __restrict__ bv,
                                                      int Ncol, int Kd, int gx) {
  __shared__ u16 Al[2][2][8192];   // [buf][kslice][row*32+k]  64 KiB
  __shared__ u16 Bl[2][2][8192];   // 64 KiB
  const int tid = threadIdx.x;
  const int w = tid >> 6, lane = tid & 63;
  const int g = lane >> 4, r = lane & 15;
  // bijective XCD swizzle (m204)
  const int nwg = (int)gridDim.x;
  const int q = nwg >> 3, rres = nwg & 7;
  const int xcd = (int)blockIdx.x & 7, lin = (int)blockIdx.x >> 3;
  const int wgid = (xcd < rres ? xcd * (q + 1) : rres * (q + 1) + (xcd - rres) * q) + lin;
  const int bm = (wgid % gx) * 256, bn = (wgid / gx) * 256;
  const int wm = (w >> 2) * 128;   // warp_m 0..1
  const int wn = (w & 3) * 64;     // warp_n 0..3

  f32x4 acc[8][4];
#pragma unroll
  for (int mi = 0; mi < 8; ++mi)
#pragma unroll
    for (int ni = 0; ni < 4; ++ni) acc[mi][ni] = f32x4{0.f, 0.f, 0.f, 0.f};

  // prologue: stage tile 0 units in pipeline order
  stage_unit(&Al[0][0][0], A, bm, Kd, 0, w, lane);
  stage_unit(&Bl[0][0][0], Bt, bn, Kd, 0, w, lane);
  stage_unit(&Al[0][1][0], A, bm, Kd, 32, w, lane);
  stage_unit(&Bl[0][1][0], Bt, bn, Kd, 32, w, lane);

#define LOADA(ks, mh) \
  _Pragma("unroll") for (int mi = 0; mi < 4; ++mi) \
    af[mi] = *(const short8*)&Al[p][ks][(wm + (mh) * 64 + mi * 16 + r) * 32 + g * 8];
#define LOADB(ks) \
  _Pragma("unroll") for (int ni = 0; ni < 4; ++ni) \
    bf[ni] = *(const short8*)&Bl[p][ks][(wn + ni * 16 + r) * 32 + g * 8];
#define MFMAQ(mh) \
  __builtin_amdgcn_s_setprio(1); \
  _Pragma("unroll") for (int mi = 0; mi < 4; ++mi) \
    _Pragma("unroll") for (int ni = 0; ni < 4; ++ni) \
      acc[(mh) * 4 + mi][ni] = __builtin_amdgcn_mfma_f32_16x16x32_bf16(af[mi], bf[ni], acc[(mh) * 4 + mi][ni], 0, 0, 0); \
  __builtin_amdgcn_s_setprio(0);

  const int NT = Kd >> 6;
  for (int t = 0; t < NT; ++t) {
    const int p = t & 1;
    const int kn = (t + 1) << 6;
    const bool pre = (t + 1 < NT);
    short8 af[4], bf[4];
    // ---- entry: A0,B0 of tile t landed (oldest 4 of 8 outstanding) ----
    asm volatile("s_waitcnt vmcnt(4)" ::: "memory");
    __builtin_amdgcn_s_barrier();
    // P1: ks0 x m-half0
    LOADA(0, 0); LOADB(0);
    if (pre) stage_unit(&Al[p ^ 1][0][0], A, bm, Kd, kn, w, lane);
    MFMAQ(0);
    // P2: ks0 x m-half1 (reuse bf)
    LOADA(0, 1);
    if (pre) stage_unit(&Bl[p ^ 1][0][0], Bt, bn, Kd, kn, w, lane);
    MFMAQ(1);
    // ---- mid: A1,B1 of tile t landed ----
    if (pre) { asm volatile("s_waitcnt vmcnt(4)" ::: "memory"); }
    else     { asm volatile("s_waitcnt vmcnt(0)" ::: "memory"); }
    __builtin_amdgcn_s_barrier();
    // P3: ks1 x m-half0
    LOADA(1, 0); LOADB(1);
    if (pre) stage_unit(&Al[p ^ 1][1][0], A, bm, Kd, kn + 32, w, lane);
    MFMAQ(0);
    // P4: ks1 x m-half1
    LOADA(1, 1);
    if (pre) stage_unit(&Bl[p ^ 1][1][0], Bt, bn, Kd, kn + 32, w, lane);
    MFMAQ(1);
  }
#undef LOADA
#undef LOADB
#undef MFMAQ

#pragma unroll
  for (int mi = 0; mi < 8; ++mi) {
#pragma unroll
    for (int ni = 0; ni < 4; ++ni) {
      const int col = bn + wn + ni * 16 + r;
      float badd = 0.f;
      if (ADD_BIAS)
        badd = (col < CN * CH) ? bq[col]
             : (col < CN * CH + CK * CH) ? bk2[col - CN * CH]
                                         : bv[col - CN * CH - CK * CH];
#pragma unroll
      for (int j = 0; j < 4; ++j) {
        const int row = bm + wm + mi * 16 + g * 4 + j;
        C[(long)row * Ncol + col] = acc[mi][ni][j] + badd;
      }
    }
  }
}

// ---------------- RoPE + scatter: q->bf16 (pre-scaled) [B][N][S][H], k->cache f32 + bf16 [B][K][S][H] ----------------
__global__ __launch_bounds__(256) void rope_scatter_kernel(const float* __restrict__ qkv,
                                                           const int* __restrict__ positions,
                                                           u16* __restrict__ qb,
                                                           u16* __restrict__ kb,
                                                           float* __restrict__ cacheK) {
  const int t = blockIdx.x;
  const int b = t / CS, s = t % CS;
  __shared__ float csv[64], snv[64];
  if (threadIdx.x < 64) {
    const int h = threadIdx.x;
    const float inv = exp2f(-(float)h * (19.931568569324174f / 64.0f)); // 1e6^(-h/64)
    const float fr = (float)positions[t] * inv;
    csv[h] = cosf(fr);
    snv[h] = sinf(fr);
  }
  __syncthreads();
  // fold softmax scale * log2(e) into q so attention scores are exp2-ready
  const float SCQ = 0.08838834764831845f * 1.4426950408889634f;
  const float* row = qkv + (long)t * QKVC;
  for (int p = threadIdx.x; p < CN * 64; p += 256) {
    const int n = p >> 6, h = p & 63;
    const float x1 = row[n * CH + h], x2 = row[n * CH + h + 64];
    const float o1 = (x1 * csv[h] - x2 * snv[h]) * SCQ;
    const float o2 = (x2 * csv[h] + x1 * snv[h]) * SCQ;
    const long qi = ((long)(b * CN + n) * CS + s) * CH + h;
    qb[qi] = f2bf(o1);
    qb[qi + 64] = f2bf(o2);
  }
  for (int p = threadIdx.x; p < CK * 64; p += 256) {
    const int kk = p >> 6, h = p & 63;
    const float x1 = row[CN * CH + kk * CH + h], x2 = row[CN * CH + kk * CH + h + 64];
    const float o1 = x1 * csv[h] - x2 * snv[h];
    const float o2 = x2 * csv[h] + x1 * snv[h];
    const long ci = ((long)(b * CS + s) * CK + kk) * CH + h;
    cacheK[ci] = o1;
    cacheK[ci + 64] = o2;
    const long ki = ((long)(b * CK + kk) * CS + s) * CH + h;
    kb[ki] = f2bf(o1);
    kb[ki + 64] = f2bf(o2);
  }
}

// ---------------- V: cache f32 write + transposed bf16 [B][K][H][S] ----------------
__global__ __launch_bounds__(256) void v_transpose_kernel(const float* __restrict__ qkv,
                                                          float* __restrict__ cacheV,
                                                          u16* __restrict__ vt) {
  __shared__ float tile[32][33];
  const int s0 = blockIdx.x * 32, h0 = blockIdx.y * 32;
  const int bz = blockIdx.z;                 // b*K + kk
  const int b = bz >> 2, kk = bz & 3;
  const int tx = threadIdx.x, ty = threadIdx.y;
#pragma unroll
  for (int i = ty; i < 32; i += 8) {
    const int s = s0 + i;
    const float v = qkv[(long)(b * CS + s) * QKVC + CN * CH + CK * CH + kk * CH + h0 + tx];
    cacheV[((long)(b * CS + s) * CK + kk) * CH + h0 + tx] = v;
    tile[i][tx] = v;
  }
  __syncthreads();
#pragma unroll
  for (int i = ty; i < 32; i += 8)
    vt[((long)bz * CH + h0 + i) * CS + s0 + tx] = f2bf(tile[tx][i]);
}

// ---------------- flash attention: 4 waves x 32 q-rows, 64 kv/step, XOR-swizzled LDS ----------------
// P slab row stride: 64 kv + 8 pad = 72 u16 (144B = 9*16B, keeps short8 reads 16B-aligned)
constexpr int PSTR = 72;
__global__ __launch_bounds__(256) void attn_kernel(const u16* __restrict__ qg,
                                                   const u16* __restrict__ kg,
                                                   const u16* __restrict__ vtg,
                                                   u16* __restrict__ og) {
  __shared__ u16 Ks[64 * 128];        // K tile [kv][h], 16B chunks XOR-swizzled by (row&7)
  __shared__ u16 Vt[128 * 64];        // V^T tile [h][kv], 16B chunks XOR-swizzled by (row&7)
  __shared__ u16 Pl[4 * 32 * PSTR];   // per-wave P slab [q][kv0..63]

  const int bn = blockIdx.y;                 // b*N + n
  const int b = bn / CN, n = bn % CN;
  const int kvh = n / CG;
  const int q0 = ((int)gridDim.x - 1 - (int)blockIdx.x) * 128;  // long blocks first
  const int tid = threadIdx.x;
  const int wid = tid >> 6, lane = tid & 63;
  const int g = lane >> 4, r = lane & 15;
  const int wq0 = q0 + wid * 32;

  // Q fragments for 32 rows (2 x 16-row tiles), kept in registers
  short8 qf[2][4];
#pragma unroll
  for (int qt = 0; qt < 2; ++qt) {
    const u16* qrp = qg + ((long)bn * CS + wq0 + qt * 16 + r) * CH;
#pragma unroll
    for (int c = 0; c < 4; ++c) qf[qt][c] = *(const short8*)(qrp + c * 32 + g * 8);
  }

  const u16* kbase = kg + (long)(b * CK + kvh) * CS * CH;   // [S][H]
  const u16* vbase = vtg + (long)(b * CK + kvh) * CH * CS;  // [H][S]

  f32x4 oacc[2][8];
#pragma unroll
  for (int qt = 0; qt < 2; ++qt)
#pragma unroll
    for (int c = 0; c < 8; ++c) oacc[qt][c] = f32x4{0.f, 0.f, 0.f, 0.f};
  float m[2] = {-INFINITY, -INFINITY};
  float l[2] = {0.f, 0.f};

  const int nsteps = q0 / 64 + 2;
  for (int it = 0; it < nsteps; ++it) {
    const int j0 = it * 64;
    __syncthreads();
    // ---- stage K tile (16KB): linear LDS dest, inverse-swizzled global src ----
#pragma unroll
    for (int c = 0; c < 4; ++c) {
      const int pbase = (wid * 4 + c) * 1024;
      const int p = pbase + lane * 16;
      const int row = p >> 8;                      // 256B per row
      const int chl = ((p >> 4) & 15) ^ (row & 7); // logical 16B-chunk
      gload16(kbase + (long)(j0 + row) * CH + (chl << 3), &Ks[pbase >> 1]);
    }
    // ---- stage V^T tile (16KB) ----
#pragma unroll
    for (int c = 0; c < 4; ++c) {
      const int pbase = (wid * 4 + c) * 1024;
      const int p = pbase + lane * 16;
      const int row = p >> 7;                      // 128B per row
      const int chl = ((p >> 4) & 7) ^ (row & 7);
      gload16(vbase + (long)row * CS + j0 + (chl << 3), &Vt[pbase >> 1]);
    }
    __syncthreads();
    if (j0 > wq0 + 31) continue;   // wave fully above diagonal (barriers already matched)

    // ---- S = K·Q^T : 32 MFMA ----
    f32x4 sc[2][4];
#pragma unroll
    for (int qt = 0; qt < 2; ++qt)
#pragma unroll
      for (int kt = 0; kt < 4; ++kt) sc[qt][kt] = f32x4{0.f, 0.f, 0.f, 0.f};
    __builtin_amdgcn_s_setprio(1);
#pragma unroll
    for (int kt = 0; kt < 4; ++kt) {
      short8 kf[4];
#pragma unroll
      for (int c = 0; c < 4; ++c)
        kf[c] = *(const short8*)&Ks[(kt * 16 + r) * 128 + ((((c << 2) + g) ^ (r & 7)) << 3)];
#pragma unroll
      for (int qt = 0; qt < 2; ++qt)
#pragma unroll
        for (int c = 0; c < 4; ++c)
          sc[qt][kt] = __builtin_amdgcn_mfma_f32_16x16x32_bf16(kf[c], qf[qt][c], sc[qt][kt], 0, 0, 0);
    }
    __builtin_amdgcn_s_setprio(0);

    // ---- causal mask (in place) + row max ----
    float pmax[2];
#pragma unroll
    for (int qt = 0; qt < 2; ++qt) {
      const int qq = wq0 + qt * 16 + r;
#pragma unroll
      for (int kt = 0; kt < 4; ++kt)
#pragma unroll
        for (int j = 0; j < 4; ++j) {
          const int kv = j0 + kt * 16 + g * 4 + j;
          if (kv > qq) sc[qt][kt][j] = -INFINITY;
        }
      float mx = sc[qt][0][0];
#pragma unroll
      for (int kt = 0; kt < 4; ++kt)
#pragma unroll
        for (int j = 0; j < 4; ++j) mx = fmaxf(mx, sc[qt][kt][j]);
      mx = fmaxf(mx, __shfl_xor(mx, 16));
      mx = fmaxf(mx, __shfl_xor(mx, 32));
      pmax[qt] = mx;
    }

    // ---- defer-max: rescale only when max grew beyond threshold ----
    const bool ok = (pmax[0] <= m[0] + 8.f) && (pmax[1] <= m[1] + 8.f);
    if (!__all(ok)) {
#pragma unroll
      for (int qt = 0; qt < 2; ++qt) {
        const float mn = fmaxf(m[qt], pmax[qt]);
        const float fac = exp2f(m[qt] - mn);
        m[qt] = mn;
        l[qt] *= fac;
#pragma unroll
        for (int j = 0; j < 4; ++j) {
          const float fj = __shfl(fac, g * 4 + j);
#pragma unroll
          for (int c = 0; c < 8; ++c) oacc[qt][c][j] *= fj;
        }
      }
    }

    // ---- P = exp2(S - m), row sum, pack to bf16, store to P slab ----
#pragma unroll
    for (int qt = 0; qt < 2; ++qt) {
      float rsum = 0.f;
#pragma unroll
      for (int kt = 0; kt < 4; ++kt) {
        const float p0 = exp2f(sc[qt][kt][0] - m[qt]);
        const float p1 = exp2f(sc[qt][kt][1] - m[qt]);
        const float p2 = exp2f(sc[qt][kt][2] - m[qt]);
        const float p3 = exp2f(sc[qt][kt][3] - m[qt]);
        rsum += (p0 + p1) + (p2 + p3);
        uint2 pk;
        pk.x = (uint32_t)f2bf(p0) | ((uint32_t)f2bf(p1) << 16);
        pk.y = (uint32_t)f2bf(p2) | ((uint32_t)f2bf(p3) << 16);
        *(uint2*)&Pl[wid * 32 * PSTR + (qt * 16 + r) * PSTR + kt * 16 + g * 4] = pk;
      }
      rsum += __shfl_xor(rsum, 16);
      rsum += __shfl_xor(rsum, 32);
      l[qt] += rsum;
    }

    // ---- O += P·V : 32 MFMA ----
    __builtin_amdgcn_s_setprio(1);
#pragma unroll
    for (int ks = 0; ks < 2; ++ks) {
      short8 pfq[2];
#pragma unroll
      for (int qt = 0; qt < 2; ++qt)
        pfq[qt] = *(const short8*)&Pl[wid * 32 * PSTR + (qt * 16 + r) * PSTR + ks * 32 + g * 8];
#pragma unroll
      for (int c = 0; c < 8; ++c) {
        const short8 vf = *(const short8*)&Vt[(c * 16 + r) * 64 + ((((ks << 2) + g) ^ (r & 7)) << 3)];
#pragma unroll
        for (int qt = 0; qt < 2; ++qt)
          oacc[qt][c] = __builtin_amdgcn_mfma_f32_16x16x32_bf16(pfq[qt], vf, oacc[qt][c], 0, 0, 0);
      }
    }
    __builtin_amdgcn_s_setprio(0);
  }

  // ---- normalize + write bf16 [t][n*H+h] ----
#pragma unroll
  for (int qt = 0; qt < 2; ++qt)
#pragma unroll
    for (int j = 0; j < 4; ++j) {
      const float linv = 1.0f / __shfl(l[qt], g * 4 + j);
      const long t = (long)b * CS + wq0 + qt * 16 + g * 4 + j;
#pragma unroll
      for (int c = 0; c < 8; ++c)
        og[t * (CN * CH) + n * CH + c * 16 + r] = f2bf(oacc[qt][c][j] * linv);
    }
}

// ---------------- host ----------------
extern "C" void kernel_launch(void* const* d_in, const int* in_sizes, int n_in,
                              void* d_out, int out_size, void* d_ws, size_t ws_size,
                              hipStream_t stream) {
  (void)in_sizes; (void)n_in; (void)out_size; (void)ws_size;
  const float* x  = (const float*)d_in[1];
  const int* positions = (const int*)d_in[2];
  const float* Wq = (const float*)d_in[3];
  const float* bq = (const float*)d_in[4];
  const float* Wk = (const float*)d_in[5];
  const float* bk = (const float*)d_in[6];
  const float* Wv = (const float*)d_in[7];
  const float* bv = (const float*)d_in[8];
  const float* Wo = (const float*)d_in[9];
  float* out = (float*)d_out;

  char* ws = (char*)d_ws;
  u16*   xb     = (u16*)(ws + 0L);            // 29,360,128 B  x bf16 [T][D]
  u16*   w1t    = (u16*)(ws + 29360128L);     // 33,030,144 B  W_qkv^T bf16 [4608][3584]
  u16*   wot    = (u16*)(ws + 62390272L);     // 25,690,112 B  Wo^T bf16 [3584][3584]
  float* qkv    = (float*)(ws + 88080384L);   // 75,497,472 B  qkv f32 [T][4608]
  u16*   attn_b = (u16*)qkv;                  // aliased: attn out bf16 [T][3584] (qkv dead by then)
  u16*   qb     = (u16*)(ws + 163577856L);    // 29,360,128 B  q roped bf16 [B][N][S][H]
  u16*   kb2    = (u16*)(ws + 192937984L);    //  4,194,304 B  k roped bf16 [B][K][S][H]
  u16*   vt     = (u16*)(ws + 197132288L);    //  4,194,304 B  V^T bf16 [B][K][H][S]
  // total 201,326,592 B

  cvt_bf16_kernel<<<dim3((CT * (long)CD) / 1024), 256, 0, stream>>>(x, xb, (long)CT * CD);
  transpose_cvt_kernel<<<dim3(112, 112), dim3(32, 8), 0, stream>>>(Wq, w1t, CD, CN * CH, 0);
  transpose_cvt_kernel<<<dim3(16, 112), dim3(32, 8), 0, stream>>>(Wk, w1t, CD, CK * CH, CN * CH);
  transpose_cvt_kernel<<<dim3(16, 112), dim3(32, 8), 0, stream>>>(Wv, w1t, CD, CK * CH, CN * CH + CK * CH);
  transpose_cvt_kernel<<<dim3(112, 112), dim3(32, 8), 0, stream>>>(Wo, wot, CN * CH, CD, 0);

  { // QKV projection: 16 x 18 = 288 blocks
    const int gx = CT / 256;
    gemm256_kernel<1><<<dim3(gx * (QKVC / 256)), 512, 0, stream>>>(xb, w1t, qkv, bq, bk, bv, QKVC, CD, gx);
  }

  rope_scatter_kernel<<<dim3(CT), 256, 0, stream>>>(qkv, positions, qb, kb2, out);
  v_transpose_kernel<<<dim3(CS / 32, CH / 32, CB * CK), dim3(32, 8), 0, stream>>>(qkv, out + KV_HALF, vt);

  attn_kernel<<<dim3(CS / 128, CB * CN), 256, 0, stream>>>(qb, kb2, vt, attn_b);

  { // O projection: 16 x 14 = 224 blocks
    const int gx = CT / 256;
    gemm256_kernel<0><<<dim3(gx * (CD / 256)), 512, 0, stream>>>(attn_b, wot, out + 2 * KV_HALF,
                                                                 nullptr, nullptr, nullptr, CD, CD, gx);
  }
}

// Round 5
// 552.014 us; speedup vs baseline: 1.2254x; 1.0092x over previous
//
#include <hip/hip_runtime.h>
#include <stdint.h>

typedef unsigned short u16;
typedef __attribute__((ext_vector_type(8))) short short8;
typedef __attribute__((ext_vector_type(4))) float f32x4;
typedef __attribute__((ext_vector_type(4))) unsigned short u16x4;

constexpr int CB = 4, CS = 1024, CD = 3584, CN = 28, CK = 4, CH = 128, CG = 7;
constexpr int CT = CB * CS;                    // 4096 tokens
constexpr int QKVC = CN * CH + 2 * CK * CH;    // 4608 fused qkv cols
constexpr long KV_HALF = (long)CB * CS * CK * CH; // 2,097,152 floats per cache half

__device__ __forceinline__ u16 f2bf(float f) {
  union { float f; uint32_t u; } c; c.f = f;
  uint32_t u = c.u + 0x7fffu + ((c.u >> 16) & 1);   // RNE to bf16
  return (u16)(u >> 16);
}

// async global->LDS, 16B per lane; LDS dest must be wave-uniform base (+lane*16 implicit)
__device__ __forceinline__ void gload16(const void* g, void* l) {
  __builtin_amdgcn_global_load_lds(
      (const __attribute__((address_space(1))) unsigned int*)(uintptr_t)g,
      (__attribute__((address_space(3))) unsigned int*)(uint32_t)(uintptr_t)l,
      16, 0, 0);
}

// ---------------- f32 -> bf16 bulk convert ----------------
__global__ __launch_bounds__(256) void cvt_bf16_kernel(const float* __restrict__ in,
                                                       u16* __restrict__ outp, long n) {
  long i = ((long)blockIdx.x * 256 + threadIdx.x) * 4;
  if (i < n) {
    const float4 v = *(const float4*)(in + i);
    u16x4 o; o.x = f2bf(v.x); o.y = f2bf(v.y); o.z = f2bf(v.z); o.w = f2bf(v.w);
    *(u16x4*)(outp + i) = o;
  }
}

// ---------------- tiled transpose f32[R][C] -> bf16 dst[(dstOff+c)][R] ----------------
__global__ __launch_bounds__(256) void transpose_cvt_kernel(const float* __restrict__ src,
                                                            u16* __restrict__ dst,
                                                            int R, int C, int dstOff) {
  __shared__ float tile[32][33];
  const int c0 = blockIdx.x * 32, r0 = blockIdx.y * 32;
  const int tx = threadIdx.x, ty = threadIdx.y;
#pragma unroll
  for (int i = ty; i < 32; i += 8)
    tile[i][tx] = src[(long)(r0 + i) * C + c0 + tx];
  __syncthreads();
#pragma unroll
  for (int i = ty; i < 32; i += 8)
    dst[(long)(dstOff + c0 + i) * R + r0 + tx] = f2bf(tile[tx][i]);
}

// ---------------- 256x256 pipelined bf16 GEMM (T2+T3+T4+T5, counted vmcnt) ----------------
// C[M][Ncol] = A[M][Kd] * Bt[Ncol][Kd]^T (+bias). 512 threads = 8 waves (2M x 4N).
// LDS: per K-tile (BK=64) 4 staging units of 16KiB (A-k0, B-k0, A-k1, B-k1), each
// [256 rows][32 k]. Rows are 64B -> banks alias every 2 rows, so 16B chunks are
// XOR-swizzled: physical_chunk = logical_chunk ^ ((row>>1)&3). Staging pre-swizzles
// the GLOBAL source (LDS dest stays linear, as global_load_lds requires); fragment
// reads apply the same XOR, which reduces to the lane-constant g ^ ((r>>1)&3).
__device__ __forceinline__ void stage_unit(u16* dst, const u16* src, int rowoff, int Kd,
                                           int kk, int w, int lane) {
  const int ci0 = (w << 7) + lane;        // 16B-chunk index; 4 chunks per 64B row
  const int ci1 = ci0 + 64;
  const int c0 = ((ci0 & 3) ^ ((ci0 >> 3) & 3)) << 3;  // inverse-swizzled col (u16 units)
  const int c1 = ((ci1 & 3) ^ ((ci1 >> 3) & 3)) << 3;
  gload16(src + (long)(rowoff + (ci0 >> 2)) * Kd + kk + c0, dst + (w << 10));
  gload16(src + (long)(rowoff + (ci1 >> 2)) * Kd + kk + c1, dst + (w << 10) + 512);
}

template <int ADD_BIAS>
__global__ __launch_bounds__(512) void gemm256_kernel(const u16* __restrict__ A,
                                                      const u16* __restrict__ Bt,
                                                      float* __restrict__ C,
                                                      const float* __restrict__ bq,
                                                      const float* __restrict__ bk2,
                                                      const float* __restrict__ bv,
                                                      int Ncol, int Kd, int gx) {
  __shared__ u16 Al[2][2][8192];   // [buf][kslice][row*32+k]  64 KiB
  __shared__ u16 Bl[2][2][8192];   // 64 KiB
  const int tid = threadIdx.x;
  const int w = tid >> 6, lane = tid & 63;
  const int g = lane >> 4, r = lane & 15;
  const int gs = (g ^ ((r >> 1) & 3)) << 3;   // swizzled fragment column (u16 units)
  // bijective XCD swizzle (m204)
  const int nwg = (int)gridDim.x;
  const int q = nwg >> 3, rres = nwg & 7;
  const int xcd = (int)blockIdx.x & 7, lin = (int)blockIdx.x >> 3;
  const int wgid = (xcd < rres ? xcd * (q + 1) : rres * (q + 1) + (xcd - rres) * q) + lin;
  const int bm = (wgid % gx) * 256, bn = (wgid / gx) * 256;
  const int wm = (w >> 2) * 128;   // warp_m 0..1
  const int wn = (w & 3) * 64;     // warp_n 0..3

  f32x4 acc[8][4];
#pragma unroll
  for (int mi = 0; mi < 8; ++mi)
#pragma unroll
    for (int ni = 0; ni < 4; ++ni) acc[mi][ni] = f32x4{0.f, 0.f, 0.f, 0.f};

  // prologue: stage tile 0 units in pipeline order
  stage_unit(&Al[0][0][0], A, bm, Kd, 0, w, lane);
  stage_unit(&Bl[0][0][0], Bt, bn, Kd, 0, w, lane);
  stage_unit(&Al[0][1][0], A, bm, Kd, 32, w, lane);
  stage_unit(&Bl[0][1][0], Bt, bn, Kd, 32, w, lane);

#define LOADA(ks, mh) \
  _Pragma("unroll") for (int mi = 0; mi < 4; ++mi) \
    af[mi] = *(const short8*)&Al[p][ks][(wm + (mh) * 64 + mi * 16 + r) * 32 + gs];
#define LOADB(ks) \
  _Pragma("unroll") for (int ni = 0; ni < 4; ++ni) \
    bf[ni] = *(const short8*)&Bl[p][ks][(wn + ni * 16 + r) * 32 + gs];
#define MFMAQ(mh) \
  __builtin_amdgcn_s_setprio(1); \
  _Pragma("unroll") for (int mi = 0; mi < 4; ++mi) \
    _Pragma("unroll") for (int ni = 0; ni < 4; ++ni) \
      acc[(mh) * 4 + mi][ni] = __builtin_amdgcn_mfma_f32_16x16x32_bf16(af[mi], bf[ni], acc[(mh) * 4 + mi][ni], 0, 0, 0); \
  __builtin_amdgcn_s_setprio(0);

  const int NT = Kd >> 6;
  for (int t = 0; t < NT; ++t) {
    const int p = t & 1;
    const int kn = (t + 1) << 6;
    const bool pre = (t + 1 < NT);
    short8 af[4], bf[4];
    // ---- entry: A0,B0 of tile t landed (oldest 4 of 8 outstanding) ----
    asm volatile("s_waitcnt vmcnt(4)" ::: "memory");
    __builtin_amdgcn_s_barrier();
    // P1: ks0 x m-half0
    LOADA(0, 0); LOADB(0);
    if (pre) stage_unit(&Al[p ^ 1][0][0], A, bm, Kd, kn, w, lane);
    MFMAQ(0);
    // P2: ks0 x m-half1 (reuse bf)
    LOADA(0, 1);
    if (pre) stage_unit(&Bl[p ^ 1][0][0], Bt, bn, Kd, kn, w, lane);
    MFMAQ(1);
    // ---- mid: A1,B1 of tile t landed ----
    if (pre) { asm volatile("s_waitcnt vmcnt(4)" ::: "memory"); }
    else     { asm volatile("s_waitcnt vmcnt(0)" ::: "memory"); }
    __builtin_amdgcn_s_barrier();
    // P3: ks1 x m-half0
    LOADA(1, 0); LOADB(1);
    if (pre) stage_unit(&Al[p ^ 1][1][0], A, bm, Kd, kn + 32, w, lane);
    MFMAQ(0);
    // P4: ks1 x m-half1
    LOADA(1, 1);
    if (pre) stage_unit(&Bl[p ^ 1][1][0], Bt, bn, Kd, kn + 32, w, lane);
    MFMAQ(1);
  }
#undef LOADA
#undef LOADB
#undef MFMAQ

#pragma unroll
  for (int mi = 0; mi < 8; ++mi) {
#pragma unroll
    for (int ni = 0; ni < 4; ++ni) {
      const int col = bn + wn + ni * 16 + r;
      float badd = 0.f;
      if (ADD_BIAS)
        badd = (col < CN * CH) ? bq[col]
             : (col < CN * CH + CK * CH) ? bk2[col - CN * CH]
                                         : bv[col - CN * CH - CK * CH];
#pragma unroll
      for (int j = 0; j < 4; ++j) {
        const int row = bm + wm + mi * 16 + g * 4 + j;
        C[(long)row * Ncol + col] = acc[mi][ni][j] + badd;
      }
    }
  }
}

// ---------------- RoPE + scatter: q->bf16 (pre-scaled) [B][N][S][H], k->cache f32 + bf16 [B][K][S][H] ----------------
__global__ __launch_bounds__(256) void rope_scatter_kernel(const float* __restrict__ qkv,
                                                           const int* __restrict__ positions,
                                                           u16* __restrict__ qb,
                                                           u16* __restrict__ kb,
                                                           float* __restrict__ cacheK) {
  const int t = blockIdx.x;
  const int b = t / CS, s = t % CS;
  __shared__ float csv[64], snv[64];
  if (threadIdx.x < 64) {
    const int h = threadIdx.x;
    const float inv = exp2f(-(float)h * (19.931568569324174f / 64.0f)); // 1e6^(-h/64)
    const float fr = (float)positions[t] * inv;
    csv[h] = cosf(fr);
    snv[h] = sinf(fr);
  }
  __syncthreads();
  // fold softmax scale * log2(e) into q so attention scores are exp2-ready
  const float SCQ = 0.08838834764831845f * 1.4426950408889634f;
  const float* row = qkv + (long)t * QKVC;
  for (int p = threadIdx.x; p < CN * 64; p += 256) {
    const int n = p >> 6, h = p & 63;
    const float x1 = row[n * CH + h], x2 = row[n * CH + h + 64];
    const float o1 = (x1 * csv[h] - x2 * snv[h]) * SCQ;
    const float o2 = (x2 * csv[h] + x1 * snv[h]) * SCQ;
    const long qi = ((long)(b * CN + n) * CS + s) * CH + h;
    qb[qi] = f2bf(o1);
    qb[qi + 64] = f2bf(o2);
  }
  for (int p = threadIdx.x; p < CK * 64; p += 256) {
    const int kk = p >> 6, h = p & 63;
    const float x1 = row[CN * CH + kk * CH + h], x2 = row[CN * CH + kk * CH + h + 64];
    const float o1 = x1 * csv[h] - x2 * snv[h];
    const float o2 = x2 * csv[h] + x1 * snv[h];
    const long ci = ((long)(b * CS + s) * CK + kk) * CH + h;
    cacheK[ci] = o1;
    cacheK[ci + 64] = o2;
    const long ki = ((long)(b * CK + kk) * CS + s) * CH + h;
    kb[ki] = f2bf(o1);
    kb[ki + 64] = f2bf(o2);
  }
}

// ---------------- V: cache f32 write + transposed bf16 [B][K][H][S] ----------------
__global__ __launch_bounds__(256) void v_transpose_kernel(const float* __restrict__ qkv,
                                                          float* __restrict__ cacheV,
                                                          u16* __restrict__ vt) {
  __shared__ float tile[32][33];
  const int s0 = blockIdx.x * 32, h0 = blockIdx.y * 32;
  const int bz = blockIdx.z;                 // b*K + kk
  const int b = bz >> 2, kk = bz & 3;
  const int tx = threadIdx.x, ty = threadIdx.y;
#pragma unroll
  for (int i = ty; i < 32; i += 8) {
    const int s = s0 + i;
    const float v = qkv[(long)(b * CS + s) * QKVC + CN * CH + CK * CH + kk * CH + h0 + tx];
    cacheV[((long)(b * CS + s) * CK + kk) * CH + h0 + tx] = v;
    tile[i][tx] = v;
  }
  __syncthreads();
#pragma unroll
  for (int i = ty; i < 32; i += 8)
    vt[((long)bz * CH + h0 + i) * CS + s0 + tx] = f2bf(tile[tx][i]);
}

// ---------------- flash attention: 4 waves x 32 q-rows, 64 kv/step, XOR-swizzled LDS ----------------
// P slab row stride: 64 kv + 8 pad = 72 u16 (144B = 9*16B, keeps short8 reads 16B-aligned)
constexpr int PSTR = 72;
__global__ __launch_bounds__(256) void attn_kernel(const u16* __restrict__ qg,
                                                   const u16* __restrict__ kg,
                                                   const u16* __restrict__ vtg,
                                                   u16* __restrict__ og) {
  __shared__ u16 Ks[64 * 128];        // K tile [kv][h], 16B chunks XOR-swizzled by (row&7)
  __shared__ u16 Vt[128 * 64];        // V^T tile [h][kv], 16B chunks XOR-swizzled by (row&7)
  __shared__ u16 Pl[4 * 32 * PSTR];   // per-wave P slab [q][kv0..63]

  const int bn = blockIdx.y;                 // b*N + n
  const int b = bn / CN, n = bn % CN;
  const int kvh = n / CG;
  const int q0 = ((int)gridDim.x - 1 - (int)blockIdx.x) * 128;  // long blocks first
  const int tid = threadIdx.x;
  const int wid = tid >> 6, lane = tid & 63;
  const int g = lane >> 4, r = lane & 15;
  const int wq0 = q0 + wid * 32;

  // Q fragments for 32 rows (2 x 16-row tiles), kept in registers
  short8 qf[2][4];
#pragma unroll
  for (int qt = 0; qt < 2; ++qt) {
    const u16* qrp = qg + ((long)bn * CS + wq0 + qt * 16 + r) * CH;
#pragma unroll
    for (int c = 0; c < 4; ++c) qf[qt][c] = *(const short8*)(qrp + c * 32 + g * 8);
  }

  const u16* kbase = kg + (long)(b * CK + kvh) * CS * CH;   // [S][H]
  const u16* vbase = vtg + (long)(b * CK + kvh) * CH * CS;  // [H][S]

  f32x4 oacc[2][8];
#pragma unroll
  for (int qt = 0; qt < 2; ++qt)
#pragma unroll
    for (int c = 0; c < 8; ++c) oacc[qt][c] = f32x4{0.f, 0.f, 0.f, 0.f};
  float m[2] = {-INFINITY, -INFINITY};
  float l[2] = {0.f, 0.f};

  const int nsteps = q0 / 64 + 2;
  for (int it = 0; it < nsteps; ++it) {
    const int j0 = it * 64;
    __syncthreads();
    // ---- stage K tile (16KB): linear LDS dest, inverse-swizzled global src ----
#pragma unroll
    for (int c = 0; c < 4; ++c) {
      const int pbase = (wid * 4 + c) * 1024;
      const int p = pbase + lane * 16;
      const int row = p >> 8;                      // 256B per row
      const int chl = ((p >> 4) & 15) ^ (row & 7); // logical 16B-chunk
      gload16(kbase + (long)(j0 + row) * CH + (chl << 3), &Ks[pbase >> 1]);
    }
    // ---- stage V^T tile (16KB) ----
#pragma unroll
    for (int c = 0; c < 4; ++c) {
      const int pbase = (wid * 4 + c) * 1024;
      const int p = pbase + lane * 16;
      const int row = p >> 7;                      // 128B per row
      const int chl = ((p >> 4) & 7) ^ (row & 7);
      gload16(vbase + (long)row * CS + j0 + (chl << 3), &Vt[pbase >> 1]);
    }
    __syncthreads();
    if (j0 > wq0 + 31) continue;   // wave fully above diagonal (barriers already matched)

    // ---- S = K·Q^T : 32 MFMA ----
    f32x4 sc[2][4];
#pragma unroll
    for (int qt = 0; qt < 2; ++qt)
#pragma unroll
      for (int kt = 0; kt < 4; ++kt) sc[qt][kt] = f32x4{0.f, 0.f, 0.f, 0.f};
    __builtin_amdgcn_s_setprio(1);
#pragma unroll
    for (int kt = 0; kt < 4; ++kt) {
      short8 kf[4];
#pragma unroll
      for (int c = 0; c < 4; ++c)
        kf[c] = *(const short8*)&Ks[(kt * 16 + r) * 128 + ((((c << 2) + g) ^ (r & 7)) << 3)];
#pragma unroll
      for (int qt = 0; qt < 2; ++qt)
#pragma unroll
        for (int c = 0; c < 4; ++c)
          sc[qt][kt] = __builtin_amdgcn_mfma_f32_16x16x32_bf16(kf[c], qf[qt][c], sc[qt][kt], 0, 0, 0);
    }
    __builtin_amdgcn_s_setprio(0);

    // ---- causal mask (in place) + row max ----
    float pmax[2];
#pragma unroll
    for (int qt = 0; qt < 2; ++qt) {
      const int qq = wq0 + qt * 16 + r;
#pragma unroll
      for (int kt = 0; kt < 4; ++kt)
#pragma unroll
        for (int j = 0; j < 4; ++j) {
          const int kv = j0 + kt * 16 + g * 4 + j;
          if (kv > qq) sc[qt][kt][j] = -INFINITY;
        }
      float mx = sc[qt][0][0];
#pragma unroll
      for (int kt = 0; kt < 4; ++kt)
#pragma unroll
        for (int j = 0; j < 4; ++j) mx = fmaxf(mx, sc[qt][kt][j]);
      mx = fmaxf(mx, __shfl_xor(mx, 16));
      mx = fmaxf(mx, __shfl_xor(mx, 32));
      pmax[qt] = mx;
    }

    // ---- defer-max: rescale only when max grew beyond threshold ----
    const bool ok = (pmax[0] <= m[0] + 8.f) && (pmax[1] <= m[1] + 8.f);
    if (!__all(ok)) {
#pragma unroll
      for (int qt = 0; qt < 2; ++qt) {
        const float mn = fmaxf(m[qt], pmax[qt]);
        const float fac = exp2f(m[qt] - mn);
        m[qt] = mn;
        l[qt] *= fac;
#pragma unroll
        for (int j = 0; j < 4; ++j) {
          const float fj = __shfl(fac, g * 4 + j);
#pragma unroll
          for (int c = 0; c < 8; ++c) oacc[qt][c][j] *= fj;
        }
      }
    }

    // ---- P = exp2(S - m), row sum, pack to bf16, store to P slab ----
#pragma unroll
    for (int qt = 0; qt < 2; ++qt) {
      float rsum = 0.f;
#pragma unroll
      for (int kt = 0; kt < 4; ++kt) {
        const float p0 = exp2f(sc[qt][kt][0] - m[qt]);
        const float p1 = exp2f(sc[qt][kt][1] - m[qt]);
        const float p2 = exp2f(sc[qt][kt][2] - m[qt]);
        const float p3 = exp2f(sc[qt][kt][3] - m[qt]);
        rsum += (p0 + p1) + (p2 + p3);
        uint2 pk;
        pk.x = (uint32_t)f2bf(p0) | ((uint32_t)f2bf(p1) << 16);
        pk.y = (uint32_t)f2bf(p2) | ((uint32_t)f2bf(p3) << 16);
        *(uint2*)&Pl[wid * 32 * PSTR + (qt * 16 + r) * PSTR + kt * 16 + g * 4] = pk;
      }
      rsum += __shfl_xor(rsum, 16);
      rsum += __shfl_xor(rsum, 32);
      l[qt] += rsum;
    }

    // ---- O += P·V : 32 MFMA ----
    __builtin_amdgcn_s_setprio(1);
#pragma unroll
    for (int ks = 0; ks < 2; ++ks) {
      short8 pfq[2];
#pragma unroll
      for (int qt = 0; qt < 2; ++qt)
        pfq[qt] = *(const short8*)&Pl[wid * 32 * PSTR + (qt * 16 + r) * PSTR + ks * 32 + g * 8];
#pragma unroll
      for (int c = 0; c < 8; ++c) {
        const short8 vf = *(const short8*)&Vt[(c * 16 + r) * 64 + ((((ks << 2) + g) ^ (r & 7)) << 3)];
#pragma unroll
        for (int qt = 0; qt < 2; ++qt)
          oacc[qt][c] = __builtin_amdgcn_mfma_f32_16x16x32_bf16(pfq[qt], vf, oacc[qt][c], 0, 0, 0);
      }
    }
    __builtin_amdgcn_s_setprio(0);
  }

  // ---- normalize + write bf16 [t][n*H+h] ----
#pragma unroll
  for (int qt = 0; qt < 2; ++qt)
#pragma unroll
    for (int j = 0; j < 4; ++j) {
      const float linv = 1.0f / __shfl(l[qt], g * 4 + j);
      const long t = (long)b * CS + wq0 + qt * 16 + g * 4 + j;
#pragma unroll
      for (int c = 0; c < 8; ++c)
        og[t * (CN * CH) + n * CH + c * 16 + r] = f2bf(oacc[qt][c][j] * linv);
    }
}

// ---------------- host ----------------
extern "C" void kernel_launch(void* const* d_in, const int* in_sizes, int n_in,
                              void* d_out, int out_size, void* d_ws, size_t ws_size,
                              hipStream_t stream) {
  (void)in_sizes; (void)n_in; (void)out_size; (void)ws_size;
  const float* x  = (const float*)d_in[1];
  const int* positions = (const int*)d_in[2];
  const float* Wq = (const float*)d_in[3];
  const float* bq = (const float*)d_in[4];
  const float* Wk = (const float*)d_in[5];
  const float* bk = (const float*)d_in[6];
  const float* Wv = (const float*)d_in[7];
  const float* bv = (const float*)d_in[8];
  const float* Wo = (const float*)d_in[9];
  float* out = (float*)d_out;

  char* ws = (char*)d_ws;
  u16*   xb     = (u16*)(ws + 0L);            // 29,360,128 B  x bf16 [T][D]
  u16*   w1t    = (u16*)(ws + 29360128L);     // 33,030,144 B  W_qkv^T bf16 [4608][3584]
  u16*   wot    = (u16*)(ws + 62390272L);     // 25,690,112 B  Wo^T bf16 [3584][3584]
  float* qkv    = (float*)(ws + 88080384L);   // 75,497,472 B  qkv f32 [T][4608]
  u16*   attn_b = (u16*)qkv;                  // aliased: attn out bf16 [T][3584] (qkv dead by then)
  u16*   qb     = (u16*)(ws + 163577856L);    // 29,360,128 B  q roped bf16 [B][N][S][H]
  u16*   kb2    = (u16*)(ws + 192937984L);    //  4,194,304 B  k roped bf16 [B][K][S][H]
  u16*   vt     = (u16*)(ws + 197132288L);    //  4,194,304 B  V^T bf16 [B][K][H][S]
  // total 201,326,592 B

  cvt_bf16_kernel<<<dim3((CT * (long)CD) / 1024), 256, 0, stream>>>(x, xb, (long)CT * CD);
  transpose_cvt_kernel<<<dim3(112, 112), dim3(32, 8), 0, stream>>>(Wq, w1t, CD, CN * CH, 0);
  transpose_cvt_kernel<<<dim3(16, 112), dim3(32, 8), 0, stream>>>(Wk, w1t, CD, CK * CH, CN * CH);
  transpose_cvt_kernel<<<dim3(16, 112), dim3(32, 8), 0, stream>>>(Wv, w1t, CD, CK * CH, CN * CH + CK * CH);
  transpose_cvt_kernel<<<dim3(112, 112), dim3(32, 8), 0, stream>>>(Wo, wot, CN * CH, CD, 0);

  { // QKV projection: 16 x 18 = 288 blocks
    const int gx = CT / 256;
    gemm256_kernel<1><<<dim3(gx * (QKVC / 256)), 512, 0, stream>>>(xb, w1t, qkv, bq, bk, bv, QKVC, CD, gx);
  }

  rope_scatter_kernel<<<dim3(CT), 256, 0, stream>>>(qkv, positions, qb, kb2, out);
  v_transpose_kernel<<<dim3(CS / 32, CH / 32, CB * CK), dim3(32, 8), 0, stream>>>(qkv, out + KV_HALF, vt);

  attn_kernel<<<dim3(CS / 128, CB * CN), 256, 0, stream>>>(qb, kb2, vt, attn_b);

  { // O projection: 16 x 14 = 224 blocks
    const int gx = CT / 256;
    gemm256_kernel<0><<<dim3(gx * (CD / 256)), 512, 0, stream>>>(attn_b, wot, out + 2 * KV_HALF,
                                                                 nullptr, nullptr, nullptr, CD, CD, gx);
  }
}

// Round 6
// 547.200 us; speedup vs baseline: 1.2362x; 1.0088x over previous
//
#include <hip/hip_runtime.h>
#include <stdint.h>

typedef unsigned short u16;
typedef __attribute__((ext_vector_type(8))) short short8;
typedef __attribute__((ext_vector_type(4))) float f32x4;
typedef __attribute__((ext_vector_type(4))) unsigned short u16x4;

constexpr int CB = 4, CS = 1024, CD = 3584, CN = 28, CK = 4, CH = 128, CG = 7;
constexpr int CT = CB * CS;                    // 4096 tokens
constexpr int QKVC = CN * CH + 2 * CK * CH;    // 4608 fused qkv cols
constexpr long KV_HALF = (long)CB * CS * CK * CH; // 2,097,152 floats per cache half

__device__ __forceinline__ u16 f2bf(float f) {
  union { float f; uint32_t u; } c; c.f = f;
  uint32_t u = c.u + 0x7fffu + ((c.u >> 16) & 1);   // RNE to bf16
  return (u16)(u >> 16);
}

// async global->LDS, 16B per lane; LDS dest must be wave-uniform base (+lane*16 implicit)
__device__ __forceinline__ void gload16(const void* g, void* l) {
  __builtin_amdgcn_global_load_lds(
      (const __attribute__((address_space(1))) unsigned int*)(uintptr_t)g,
      (__attribute__((address_space(3))) unsigned int*)(uint32_t)(uintptr_t)l,
      16, 0, 0);
}

// ---------------- f32 -> bf16 bulk convert ----------------
__global__ __launch_bounds__(256) void cvt_bf16_kernel(const float* __restrict__ in,
                                                       u16* __restrict__ outp, long n) {
  long i = ((long)blockIdx.x * 256 + threadIdx.x) * 4;
  if (i < n) {
    const float4 v = *(const float4*)(in + i);
    u16x4 o; o.x = f2bf(v.x); o.y = f2bf(v.y); o.z = f2bf(v.z); o.w = f2bf(v.w);
    *(u16x4*)(outp + i) = o;
  }
}

// ---------------- tiled transpose f32[R][C] -> bf16 dst[(dstOff+c)][R] ----------------
__global__ __launch_bounds__(256) void transpose_cvt_kernel(const float* __restrict__ src,
                                                            u16* __restrict__ dst,
                                                            int R, int C, int dstOff) {
  __shared__ float tile[32][33];
  const int c0 = blockIdx.x * 32, r0 = blockIdx.y * 32;
  const int tx = threadIdx.x, ty = threadIdx.y;
#pragma unroll
  for (int i = ty; i < 32; i += 8)
    tile[i][tx] = src[(long)(r0 + i) * C + c0 + tx];
  __syncthreads();
#pragma unroll
  for (int i = ty; i < 32; i += 8)
    dst[(long)(dstOff + c0 + i) * R + r0 + tx] = f2bf(tile[tx][i]);
}

// ---------------- 256x256 pipelined bf16 GEMM (T2+T3+T4+T5, counted vmcnt) ----------------
__device__ __forceinline__ void stage_unit(u16* dst, const u16* src, int rowoff, int Kd,
                                           int kk, int w, int lane) {
  const int ci0 = (w << 7) + lane;        // 16B-chunk index; 4 chunks per 64B row
  const int ci1 = ci0 + 64;
  const int c0 = ((ci0 & 3) ^ ((ci0 >> 3) & 3)) << 3;  // inverse-swizzled col (u16 units)
  const int c1 = ((ci1 & 3) ^ ((ci1 >> 3) & 3)) << 3;
  gload16(src + (long)(rowoff + (ci0 >> 2)) * Kd + kk + c0, dst + (w << 10));
  gload16(src + (long)(rowoff + (ci1 >> 2)) * Kd + kk + c1, dst + (w << 10) + 512);
}

template <int ADD_BIAS>
__global__ __launch_bounds__(512) void gemm256_kernel(const u16* __restrict__ A,
                                                      const u16* __restrict__ Bt,
                                                      float* __restrict__ C,
                                                      const float* __restrict__ bq,
                                                      const float* __restrict__ bk2,
                                                      const float* __restrict__ bv,
                                                      int Ncol, int Kd, int gx) {
  __shared__ u16 Al[2][2][8192];   // [buf][kslice][row*32+k]  64 KiB
  __shared__ u16 Bl[2][2][8192];   // 64 KiB
  const int tid = threadIdx.x;
  const int w = tid >> 6, lane = tid & 63;
  const int g = lane >> 4, r = lane & 15;
  const int gs = (g ^ ((r >> 1) & 3)) << 3;   // swizzled fragment column (u16 units)
  // bijective XCD swizzle (m204)
  const int nwg = (int)gridDim.x;
  const int q = nwg >> 3, rres = nwg & 7;
  const int xcd = (int)blockIdx.x & 7, lin = (int)blockIdx.x >> 3;
  const int wgid = (xcd < rres ? xcd * (q + 1) : rres * (q + 1) + (xcd - rres) * q) + lin;
  const int bm = (wgid % gx) * 256, bn = (wgid / gx) * 256;
  const int wm = (w >> 2) * 128;   // warp_m 0..1
  const int wn = (w & 3) * 64;     // warp_n 0..3

  f32x4 acc[8][4];
#pragma unroll
  for (int mi = 0; mi < 8; ++mi)
#pragma unroll
    for (int ni = 0; ni < 4; ++ni) acc[mi][ni] = f32x4{0.f, 0.f, 0.f, 0.f};

  // prologue: stage tile 0 units in pipeline order
  stage_unit(&Al[0][0][0], A, bm, Kd, 0, w, lane);
  stage_unit(&Bl[0][0][0], Bt, bn, Kd, 0, w, lane);
  stage_unit(&Al[0][1][0], A, bm, Kd, 32, w, lane);
  stage_unit(&Bl[0][1][0], Bt, bn, Kd, 32, w, lane);

#define LOADA(ks, mh) \
  _Pragma("unroll") for (int mi = 0; mi < 4; ++mi) \
    af[mi] = *(const short8*)&Al[p][ks][(wm + (mh) * 64 + mi * 16 + r) * 32 + gs];
#define LOADB(ks) \
  _Pragma("unroll") for (int ni = 0; ni < 4; ++ni) \
    bf[ni] = *(const short8*)&Bl[p][ks][(wn + ni * 16 + r) * 32 + gs];
#define MFMAQ(mh) \
  __builtin_amdgcn_s_setprio(1); \
  _Pragma("unroll") for (int mi = 0; mi < 4; ++mi) \
    _Pragma("unroll") for (int ni = 0; ni < 4; ++ni) \
      acc[(mh) * 4 + mi][ni] = __builtin_amdgcn_mfma_f32_16x16x32_bf16(af[mi], bf[ni], acc[(mh) * 4 + mi][ni], 0, 0, 0); \
  __builtin_amdgcn_s_setprio(0);

  const int NT = Kd >> 6;
  for (int t = 0; t < NT; ++t) {
    const int p = t & 1;
    const int kn = (t + 1) << 6;
    const bool pre = (t + 1 < NT);
    short8 af[4], bf[4];
    // ---- entry: A0,B0 of tile t landed (oldest 4 of 8 outstanding) ----
    asm volatile("s_waitcnt vmcnt(4)" ::: "memory");
    __builtin_amdgcn_s_barrier();
    // P1: ks0 x m-half0
    LOADA(0, 0); LOADB(0);
    if (pre) stage_unit(&Al[p ^ 1][0][0], A, bm, Kd, kn, w, lane);
    MFMAQ(0);
    // P2: ks0 x m-half1 (reuse bf)
    LOADA(0, 1);
    if (pre) stage_unit(&Bl[p ^ 1][0][0], Bt, bn, Kd, kn, w, lane);
    MFMAQ(1);
    // ---- mid: A1,B1 of tile t landed ----
    if (pre) { asm volatile("s_waitcnt vmcnt(4)" ::: "memory"); }
    else     { asm volatile("s_waitcnt vmcnt(0)" ::: "memory"); }
    __builtin_amdgcn_s_barrier();
    // P3: ks1 x m-half0
    LOADA(1, 0); LOADB(1);
    if (pre) stage_unit(&Al[p ^ 1][1][0], A, bm, Kd, kn + 32, w, lane);
    MFMAQ(0);
    // P4: ks1 x m-half1
    LOADA(1, 1);
    if (pre) stage_unit(&Bl[p ^ 1][1][0], Bt, bn, Kd, kn + 32, w, lane);
    MFMAQ(1);
  }
#undef LOADA
#undef LOADB
#undef MFMAQ

#pragma unroll
  for (int mi = 0; mi < 8; ++mi) {
#pragma unroll
    for (int ni = 0; ni < 4; ++ni) {
      const int col = bn + wn + ni * 16 + r;
      float badd = 0.f;
      if (ADD_BIAS)
        badd = (col < CN * CH) ? bq[col]
             : (col < CN * CH + CK * CH) ? bk2[col - CN * CH]
                                         : bv[col - CN * CH - CK * CH];
#pragma unroll
      for (int j = 0; j < 4; ++j) {
        const int row = bm + wm + mi * 16 + g * 4 + j;
        C[(long)row * Ncol + col] = acc[mi][ni][j] + badd;
      }
    }
  }
}

// ---------------- RoPE + scatter: q->bf16 (pre-scaled) [B][N][S][H], k->cache f32 + bf16 [B][K][S][H] ----------------
__global__ __launch_bounds__(256) void rope_scatter_kernel(const float* __restrict__ qkv,
                                                           const int* __restrict__ positions,
                                                           u16* __restrict__ qb,
                                                           u16* __restrict__ kb,
                                                           float* __restrict__ cacheK) {
  const int t = blockIdx.x;
  const int b = t / CS, s = t % CS;
  __shared__ float csv[64], snv[64];
  if (threadIdx.x < 64) {
    const int h = threadIdx.x;
    const float inv = exp2f(-(float)h * (19.931568569324174f / 64.0f)); // 1e6^(-h/64)
    const float fr = (float)positions[t] * inv;
    csv[h] = cosf(fr);
    snv[h] = sinf(fr);
  }
  __syncthreads();
  // fold softmax scale * log2(e) into q so attention scores are exp2-ready
  const float SCQ = 0.08838834764831845f * 1.4426950408889634f;
  const float* row = qkv + (long)t * QKVC;
  for (int p = threadIdx.x; p < CN * 64; p += 256) {
    const int n = p >> 6, h = p & 63;
    const float x1 = row[n * CH + h], x2 = row[n * CH + h + 64];
    const float o1 = (x1 * csv[h] - x2 * snv[h]) * SCQ;
    const float o2 = (x2 * csv[h] + x1 * snv[h]) * SCQ;
    const long qi = ((long)(b * CN + n) * CS + s) * CH + h;
    qb[qi] = f2bf(o1);
    qb[qi + 64] = f2bf(o2);
  }
  for (int p = threadIdx.x; p < CK * 64; p += 256) {
    const int kk = p >> 6, h = p & 63;
    const float x1 = row[CN * CH + kk * CH + h], x2 = row[CN * CH + kk * CH + h + 64];
    const float o1 = x1 * csv[h] - x2 * snv[h];
    const float o2 = x2 * csv[h] + x1 * snv[h];
    const long ci = ((long)(b * CS + s) * CK + kk) * CH + h;
    cacheK[ci] = o1;
    cacheK[ci + 64] = o2;
    const long ki = ((long)(b * CK + kk) * CS + s) * CH + h;
    kb[ki] = f2bf(o1);
    kb[ki + 64] = f2bf(o2);
  }
}

// ---------------- V: cache f32 write + transposed bf16 [B][K][H][S] ----------------
__global__ __launch_bounds__(256) void v_transpose_kernel(const float* __restrict__ qkv,
                                                          float* __restrict__ cacheV,
                                                          u16* __restrict__ vt) {
  __shared__ float tile[32][33];
  const int s0 = blockIdx.x * 32, h0 = blockIdx.y * 32;
  const int bz = blockIdx.z;                 // b*K + kk
  const int b = bz >> 2, kk = bz & 3;
  const int tx = threadIdx.x, ty = threadIdx.y;
#pragma unroll
  for (int i = ty; i < 32; i += 8) {
    const int s = s0 + i;
    const float v = qkv[(long)(b * CS + s) * QKVC + CN * CH + CK * CH + kk * CH + h0 + tx];
    cacheV[((long)(b * CS + s) * CK + kk) * CH + h0 + tx] = v;
    tile[i][tx] = v;
  }
  __syncthreads();
#pragma unroll
  for (int i = ty; i < 32; i += 8)
    vt[((long)bz * CH + h0 + i) * CS + s0 + tx] = f2bf(tile[tx][i]);
}

// ---------------- flash attention: 4 waves x 32 q-rows, 64 kv/step ----------------
// Double-buffered K/V LDS + counted-vmcnt prefetch (T3+T4): stage step t+1 before
// computing step t; vmcnt(8) keeps next-step loads in flight across barriers.
constexpr int PSTR = 72;
__global__ __launch_bounds__(256) void attn_kernel(const u16* __restrict__ qg,
                                                   const u16* __restrict__ kg,
                                                   const u16* __restrict__ vtg,
                                                   u16* __restrict__ og) {
  __shared__ u16 Ks[2][64 * 128];     // K tile [kv][h], 16B chunks XOR-swizzled by (row&7)
  __shared__ u16 Vt[2][128 * 64];     // V^T tile [h][kv], swizzled likewise
  __shared__ u16 Pl[4 * 32 * PSTR];   // per-wave P slab [q][kv0..63]

  const int bn = blockIdx.y;                 // b*N + n
  const int b = bn / CN, n = bn % CN;
  const int kvh = n / CG;
  const int q0 = ((int)gridDim.x - 1 - (int)blockIdx.x) * 128;  // long blocks first
  const int tid = threadIdx.x;
  const int wid = tid >> 6, lane = tid & 63;
  const int g = lane >> 4, r = lane & 15;
  const int wq0 = q0 + wid * 32;

  // Q fragments for 32 rows (2 x 16-row tiles), kept in registers
  short8 qf[2][4];
#pragma unroll
  for (int qt = 0; qt < 2; ++qt) {
    const u16* qrp = qg + ((long)bn * CS + wq0 + qt * 16 + r) * CH;
#pragma unroll
    for (int c = 0; c < 4; ++c) qf[qt][c] = *(const short8*)(qrp + c * 32 + g * 8);
  }

  const u16* kbase = kg + (long)(b * CK + kvh) * CS * CH;   // [S][H]
  const u16* vbase = vtg + (long)(b * CK + kvh) * CH * CS;  // [H][S]

#define STAGE_KV(bufidx, jj) do { \
  _Pragma("unroll") for (int c = 0; c < 4; ++c) { \
    const int pbase = (wid * 4 + c) * 1024; \
    const int pp = pbase + lane * 16; \
    const int row = pp >> 8; \
    const int chl = ((pp >> 4) & 15) ^ (row & 7); \
    gload16(kbase + (long)((jj) + row) * CH + (chl << 3), &Ks[bufidx][pbase >> 1]); \
  } \
  _Pragma("unroll") for (int c = 0; c < 4; ++c) { \
    const int pbase = (wid * 4 + c) * 1024; \
    const int pp = pbase + lane * 16; \
    const int row = pp >> 7; \
    const int chl = ((pp >> 4) & 7) ^ (row & 7); \
    gload16(vbase + (long)row * CS + (jj) + (chl << 3), &Vt[bufidx][pbase >> 1]); \
  } \
} while (0)

  f32x4 oacc[2][8];
#pragma unroll
  for (int qt = 0; qt < 2; ++qt)
#pragma unroll
    for (int c = 0; c < 8; ++c) oacc[qt][c] = f32x4{0.f, 0.f, 0.f, 0.f};
  float m[2] = {-INFINITY, -INFINITY};
  float l[2] = {0.f, 0.f};

  const int nsteps = q0 / 64 + 2;
  STAGE_KV(0, 0);   // prologue: 8 loads in flight
  for (int it = 0; it < nsteps; ++it) {
    const int j0 = it * 64;
    const int cur = it & 1;
    if (it + 1 < nsteps) {
      STAGE_KV(cur ^ 1, j0 + 64);                       // issue next step's 8 loads
      asm volatile("s_waitcnt vmcnt(8)" ::: "memory");  // wait only for current step's 8
    } else {
      asm volatile("s_waitcnt vmcnt(0)" ::: "memory");
    }
    __builtin_amdgcn_s_barrier();

    if (j0 <= wq0 + 31) {
      // ---- S = K·Q^T : 32 MFMA ----
      f32x4 sc[2][4];
#pragma unroll
      for (int qt = 0; qt < 2; ++qt)
#pragma unroll
        for (int kt = 0; kt < 4; ++kt) sc[qt][kt] = f32x4{0.f, 0.f, 0.f, 0.f};
      __builtin_amdgcn_s_setprio(1);
#pragma unroll
      for (int kt = 0; kt < 4; ++kt) {
        short8 kf[4];
#pragma unroll
        for (int c = 0; c < 4; ++c)
          kf[c] = *(const short8*)&Ks[cur][(kt * 16 + r) * 128 + ((((c << 2) + g) ^ (r & 7)) << 3)];
#pragma unroll
        for (int qt = 0; qt < 2; ++qt)
#pragma unroll
          for (int c = 0; c < 4; ++c)
            sc[qt][kt] = __builtin_amdgcn_mfma_f32_16x16x32_bf16(kf[c], qf[qt][c], sc[qt][kt], 0, 0, 0);
      }
      __builtin_amdgcn_s_setprio(0);

      // ---- causal mask (in place) + row max ----
      float pmax[2];
#pragma unroll
      for (int qt = 0; qt < 2; ++qt) {
        const int qq = wq0 + qt * 16 + r;
#pragma unroll
        for (int kt = 0; kt < 4; ++kt)
#pragma unroll
          for (int j = 0; j < 4; ++j) {
            const int kv = j0 + kt * 16 + g * 4 + j;
            if (kv > qq) sc[qt][kt][j] = -INFINITY;
          }
        float mx = sc[qt][0][0];
#pragma unroll
        for (int kt = 0; kt < 4; ++kt)
#pragma unroll
          for (int j = 0; j < 4; ++j) mx = fmaxf(mx, sc[qt][kt][j]);
        mx = fmaxf(mx, __shfl_xor(mx, 16));
        mx = fmaxf(mx, __shfl_xor(mx, 32));
        pmax[qt] = mx;
      }

      // ---- defer-max: rescale only when max grew beyond threshold ----
      const bool ok = (pmax[0] <= m[0] + 8.f) && (pmax[1] <= m[1] + 8.f);
      if (!__all(ok)) {
#pragma unroll
        for (int qt = 0; qt < 2; ++qt) {
          const float mn = fmaxf(m[qt], pmax[qt]);
          const float fac = exp2f(m[qt] - mn);
          m[qt] = mn;
          l[qt] *= fac;
#pragma unroll
          for (int j = 0; j < 4; ++j) {
            const float fj = __shfl(fac, g * 4 + j);
#pragma unroll
            for (int c = 0; c < 8; ++c) oacc[qt][c][j] *= fj;
          }
        }
      }

      // ---- P = exp2(S - m), row sum, pack to bf16, store to P slab ----
#pragma unroll
      for (int qt = 0; qt < 2; ++qt) {
        float rsum = 0.f;
#pragma unroll
        for (int kt = 0; kt < 4; ++kt) {
          const float p0 = exp2f(sc[qt][kt][0] - m[qt]);
          const float p1 = exp2f(sc[qt][kt][1] - m[qt]);
          const float p2 = exp2f(sc[qt][kt][2] - m[qt]);
          const float p3 = exp2f(sc[qt][kt][3] - m[qt]);
          rsum += (p0 + p1) + (p2 + p3);
          uint2 pk;
          pk.x = (uint32_t)f2bf(p0) | ((uint32_t)f2bf(p1) << 16);
          pk.y = (uint32_t)f2bf(p2) | ((uint32_t)f2bf(p3) << 16);
          *(uint2*)&Pl[wid * 32 * PSTR + (qt * 16 + r) * PSTR + kt * 16 + g * 4] = pk;
        }
        rsum += __shfl_xor(rsum, 16);
        rsum += __shfl_xor(rsum, 32);
        l[qt] += rsum;
      }

      // ---- O += P·V : 32 MFMA ----
      __builtin_amdgcn_s_setprio(1);
#pragma unroll
      for (int ks = 0; ks < 2; ++ks) {
        short8 pfq[2];
#pragma unroll
        for (int qt = 0; qt < 2; ++qt)
          pfq[qt] = *(const short8*)&Pl[wid * 32 * PSTR + (qt * 16 + r) * PSTR + ks * 32 + g * 8];
#pragma unroll
        for (int c = 0; c < 8; ++c) {
          const short8 vf = *(const short8*)&Vt[cur][(c * 16 + r) * 64 + ((((ks << 2) + g) ^ (r & 7)) << 3)];
#pragma unroll
          for (int qt = 0; qt < 2; ++qt)
            oacc[qt][c] = __builtin_amdgcn_mfma_f32_16x16x32_bf16(pfq[qt], vf, oacc[qt][c], 0, 0, 0);
        }
      }
      __builtin_amdgcn_s_setprio(0);
    }

    __builtin_amdgcn_s_barrier();   // protect buf cur from being re-staged next iter
  }
#undef STAGE_KV

  // ---- normalize + write bf16 [t][n*H+h] ----
#pragma unroll
  for (int qt = 0; qt < 2; ++qt)
#pragma unroll
    for (int j = 0; j < 4; ++j) {
      const float linv = 1.0f / __shfl(l[qt], g * 4 + j);
      const long t = (long)b * CS + wq0 + qt * 16 + g * 4 + j;
#pragma unroll
      for (int c = 0; c < 8; ++c)
        og[t * (CN * CH) + n * CH + c * 16 + r] = f2bf(oacc[qt][c][j] * linv);
    }
}

// ---------------- host ----------------
extern "C" void kernel_launch(void* const* d_in, const int* in_sizes, int n_in,
                              void* d_out, int out_size, void* d_ws, size_t ws_size,
                              hipStream_t stream) {
  (void)in_sizes; (void)n_in; (void)out_size; (void)ws_size;
  const float* x  = (const float*)d_in[1];
  const int* positions = (const int*)d_in[2];
  const float* Wq = (const float*)d_in[3];
  const float* bq = (const float*)d_in[4];
  const float* Wk = (const float*)d_in[5];
  const float* bk = (const float*)d_in[6];
  const float* Wv = (const float*)d_in[7];
  const float* bv = (const float*)d_in[8];
  const float* Wo = (const float*)d_in[9];
  float* out = (float*)d_out;

  char* ws = (char*)d_ws;
  u16*   xb     = (u16*)(ws + 0L);            // 29,360,128 B  x bf16 [T][D]
  u16*   w1t    = (u16*)(ws + 29360128L);     // 33,030,144 B  W_qkv^T bf16 [4608][3584]
  u16*   wot    = (u16*)(ws + 62390272L);     // 25,690,112 B  Wo^T bf16 [3584][3584]
  float* qkv    = (float*)(ws + 88080384L);   // 75,497,472 B  qkv f32 [T][4608]
  u16*   attn_b = (u16*)qkv;                  // aliased: attn out bf16 [T][3584] (qkv dead by then)
  u16*   qb     = (u16*)(ws + 163577856L);    // 29,360,128 B  q roped bf16 [B][N][S][H]
  u16*   kb2    = (u16*)(ws + 192937984L);    //  4,194,304 B  k roped bf16 [B][K][S][H]
  u16*   vt     = (u16*)(ws + 197132288L);    //  4,194,304 B  V^T bf16 [B][K][H][S]
  // total 201,326,592 B

  cvt_bf16_kernel<<<dim3((CT * (long)CD) / 1024), 256, 0, stream>>>(x, xb, (long)CT * CD);
  transpose_cvt_kernel<<<dim3(112, 112), dim3(32, 8), 0, stream>>>(Wq, w1t, CD, CN * CH, 0);
  transpose_cvt_kernel<<<dim3(16, 112), dim3(32, 8), 0, stream>>>(Wk, w1t, CD, CK * CH, CN * CH);
  transpose_cvt_kernel<<<dim3(16, 112), dim3(32, 8), 0, stream>>>(Wv, w1t, CD, CK * CH, CN * CH + CK * CH);
  transpose_cvt_kernel<<<dim3(112, 112), dim3(32, 8), 0, stream>>>(Wo, wot, CN * CH, CD, 0);

  { // QKV projection: 16 x 18 = 288 blocks
    const int gx = CT / 256;
    gemm256_kernel<1><<<dim3(gx * (QKVC / 256)), 512, 0, stream>>>(xb, w1t, qkv, bq, bk, bv, QKVC, CD, gx);
  }

  rope_scatter_kernel<<<dim3(CT), 256, 0, stream>>>(qkv, positions, qb, kb2, out);
  v_transpose_kernel<<<dim3(CS / 32, CH / 32, CB * CK), dim3(32, 8), 0, stream>>>(qkv, out + KV_HALF, vt);

  attn_kernel<<<dim3(CS / 128, CB * CN), 256, 0, stream>>>(qb, kb2, vt, attn_b);

  { // O projection: 16 x 14 = 224 blocks
    const int gx = CT / 256;
    gemm256_kernel<0><<<dim3(gx * (CD / 256)), 512, 0, stream>>>(attn_b, wot, out + 2 * KV_HALF,
                                                                 nullptr, nullptr, nullptr, CD, CD, gx);
  }
}